// Round 1
// baseline (477.807 us; speedup 1.0000x reference)
//
#include <hip/hip_runtime.h>
#include <hip/hip_bf16.h>

// Shapes (fixed by the problem)
#define VV 50000
#define EE 128
#define HH 128
#define OO 128
#define BB 64
#define TT 512

typedef __bf16 bf16_t;
typedef __attribute__((ext_vector_type(8))) __bf16 bf16x8;
typedef __attribute__((ext_vector_type(4))) __bf16 bf16x4;
typedef __attribute__((ext_vector_type(4))) float floatx4;

__device__ __forceinline__ bf16x8 ldb8(const bf16_t* p) {
    return *reinterpret_cast<const bf16x8*>(p);
}

// load 8 consecutive fp32, round to bf16 fragment (two float4 loads)
__device__ __forceinline__ bf16x8 ldf8_bf(const float* p) {
    const float4* q = reinterpret_cast<const float4*>(p);
    float4 u = q[0], v = q[1];
    bf16x8 r;
    r[0] = (__bf16)u.x; r[1] = (__bf16)u.y; r[2] = (__bf16)u.z; r[3] = (__bf16)u.w;
    r[4] = (__bf16)v.x; r[5] = (__bf16)v.y; r[6] = (__bf16)v.z; r[7] = (__bf16)v.w;
    return r;
}

__device__ __forceinline__ float fast_rcp(float x) { return __builtin_amdgcn_rcpf(x); }
__device__ __forceinline__ float sigmoid_f(float x) {
    return fast_rcp(1.0f + __expf(-x));
}
__device__ __forceinline__ float tanh_f(float x) {
    float e = __expf(2.0f * x);
    return 1.0f - 2.0f * fast_rcp(e + 1.0f);
}

// LDS-only barrier: wait LDS ops, sync — do NOT drain vmcnt (hist stores and
// gx ring-prefetch loads stay in flight across steps).
__device__ __forceinline__ void lds_barrier() {
    asm volatile("s_waitcnt lgkmcnt(0)\n\ts_barrier" ::: "memory");
}

// select D-reg by quad (D row = quad*4 + r -> sample = r; picking r = quad
// gives row 5*quad -> sample quad since 5 == 1 mod 4)
__device__ __forceinline__ float sel4(floatx4 v, bool lowquad, bool lowhalf) {
    return lowhalf ? (lowquad ? v[0] : v[1]) : (lowquad ? v[2] : v[3]);
}

// -------- K0: preconvert small weights fp32->bf16 + fold gx bias.
__global__ __launch_bounds__(256) void k0_conv(
    const float* __restrict__ we,
    const float* __restrict__ wihf, const float* __restrict__ wihb,
    const float* __restrict__ whhf, const float* __restrict__ whhb,
    const float* __restrict__ wh2o,
    const float* __restrict__ bihf, const float* __restrict__ bhhf,
    const float* __restrict__ bihb, const float* __restrict__ bhhb,
    bf16_t* __restrict__ we_bf,
    bf16_t* __restrict__ wih_bf, bf16_t* __restrict__ whh_bf,
    bf16_t* __restrict__ wh2o_bf, float* __restrict__ gxbias) {
    int tid = blockIdx.x * 256 + threadIdx.x;
    int np = gridDim.x * 256;
    for (int i = tid; i < HH * EE; i += np) we_bf[i] = (bf16_t)we[i];
    for (int i = tid; i < 384 * HH; i += np) {
        wih_bf[i] = (bf16_t)wihf[i];
        wih_bf[384 * HH + i] = (bf16_t)wihb[i];
        whh_bf[i] = (bf16_t)whhf[i];
        whh_bf[384 * HH + i] = (bf16_t)whhb[i];
    }
    for (int i = tid; i < OO * 256; i += np) wh2o_bf[i] = (bf16_t)wh2o[i];
    if (tid < 768) {
        int dir = tid / 384, n = tid % 384;
        const float* bih = dir ? bihb : bihf;
        const float* bhh = dir ? bhhb : bhhf;
        gxbias[tid] = bih[n] + (n < 256 ? bhh[n] : 0.0f);  // bhh_n goes in K3's C-init
    }
}

// -------- K12 (fused K1+K2), 4 timesteps per block, with dead-time skip:
// lens sorted descending -> tile g's max len = lens[16g]; blocks entirely past
// it produce gx no one reads (K3 stops at its group Lmax <= lens[16g]).
__global__ __launch_bounds__(256) void k12_gx(const int* __restrict__ X,
                                              const float* __restrict__ emb,
                                              const bf16_t* __restrict__ we_bf,
                                              const float* __restrict__ be,
                                              const bf16_t* __restrict__ wih_bf,
                                              const float* __restrict__ gxbias,
                                              const int* __restrict__ lens,
                                              bf16_t* __restrict__ gx3) {
    int blk = blockIdx.x;            // 0..511 = tq*4 + g
    int tq = blk >> 2;
    int g = blk & 3;                 // 16-sample tile
    if (4 * tq >= lens[16 * g]) return;   // uniform: whole block dead

    int lane = threadIdx.x & 63;
    int w2 = threadIdx.x >> 6;       // wave 0..3
    int quad = lane >> 4, col = lane & 15;

    __shared__ bf16_t xs[4][16 * 136];   // 4 xh tiles, row-padded

    // stage 1 x4: xh = emb[X] @ We^T + be (A rows = 16 samples at t=4tq+tt)
#pragma unroll
    for (int tt = 0; tt < 4; ++tt) {
        int t = 4 * tq + tt;
        int v = X[(g * 16 + col) * TT + t];
        bf16x8 a[4];
#pragma unroll
        for (int kc = 0; kc < 4; ++kc)
            a[kc] = ldf8_bf(emb + (size_t)v * EE + kc * 32 + quad * 8);
#pragma unroll
        for (int tl = 0; tl < 2; ++tl) {
            int n = 32 * w2 + 16 * tl + col;
            floatx4 acc = {0.f, 0.f, 0.f, 0.f};
#pragma unroll
            for (int kc = 0; kc < 4; ++kc) {
                bf16x8 bw = ldb8(we_bf + (size_t)n * EE + kc * 32 + quad * 8);
                acc = __builtin_amdgcn_mfma_f32_16x16x32_bf16(a[kc], bw, acc, 0, 0, 0);
            }
            float bias = be[n];
#pragma unroll
            for (int r = 0; r < 4; ++r)
                xs[tt][(quad * 4 + r) * 136 + n] = (bf16_t)(acc[r] + bias);
        }
    }
    __syncthreads();

    // stage 2: gx = xh @ Wih^T + gxbias, both dirs; Wih loaded once per n-tile
    bf16x8 a2[4][4];
#pragma unroll
    for (int tt = 0; tt < 4; ++tt)
#pragma unroll
        for (int kc = 0; kc < 4; ++kc)
            a2[tt][kc] = ldb8(xs[tt] + col * 136 + kc * 32 + quad * 8);

#pragma unroll
    for (int tl = 0; tl < 12; ++tl) {
        int idx = w2 * 12 + tl;          // 0..47
        int dir = idx >= 24;
        int n = (idx - dir * 24) * 16 + col;   // 0..383
        bf16x8 bw[4];
#pragma unroll
        for (int kc = 0; kc < 4; ++kc)
            bw[kc] = ldb8(wih_bf + ((size_t)dir * 384 + n) * HH + kc * 32 + quad * 8);
        float bias = gxbias[dir * 384 + n];
#pragma unroll
        for (int tt = 0; tt < 4; ++tt) {
            int t = 4 * tq + tt;
            floatx4 acc = {0.f, 0.f, 0.f, 0.f};
#pragma unroll
            for (int kc = 0; kc < 4; ++kc)
                acc = __builtin_amdgcn_mfma_f32_16x16x32_bf16(a2[tt][kc], bw[kc], acc, 0, 0, 0);
            bf16x4 pack;
#pragma unroll
            for (int r = 0; r < 4; ++r)
                pack[r] = (__bf16)(acc[r] + bias);   // D row r -> sample 16g+quad*4+r
            *reinterpret_cast<bf16x4*>(
                gx3 + (((size_t)(dir * 16 + 4 * g + quad) * TT + t) * 384 + n) * 4) = pack;
        }
    }
}

// -------- K3: masked GRU recurrence.
// NEW (this round): 4 waves (256 thr) instead of 8; each lane owns TWO hidden
// columns (j, j+64) of its sample (=quad). Rationale: all waves read the
// IDENTICAL broadcast A-fragment from LDS (aoff depends only on col,quad), so
// 8 waves paid 32 ds_read_b128/step of LDS-unit occupancy (~380 cy); 4 waves
// pay half. Also 1 wave/SIMD removes issue contention and the K=128 MFMA
// accumulation is split into two independent 2-deep chains (select per half,
// add after) to halve MFMA dependency latency on the serial path.
#define HPAD 144
#define HBUF (4 * HPAD)
__global__ __launch_bounds__(256, 1) void k3_gru(const bf16_t* __restrict__ gx3,
                                                 const bf16_t* __restrict__ whh_bf,
                                                 const float* __restrict__ bhh_f,
                                                 const float* __restrict__ bhh_b,
                                                 const int* __restrict__ lens,
                                                 bf16_t* __restrict__ hist2) {
    int g16 = blockIdx.x;    // 4-sample group: samples 4*g16 .. 4*g16+3
    int dir = blockIdx.y;
    const float* bhh = dir ? bhh_b : bhh_f;

    int tid = threadIdx.x;
    int w = tid >> 6;        // wave 0..3
    int lane = tid & 63;
    int quad = lane >> 4, col = lane & 15;
    int j0 = 16 * w + col;   // owned hidden columns j0 (0..63) and j0+64
    int j1 = j0 + 64;

    __shared__ bf16_t hl[2 * HBUF];   // double-buffered h, 4 rows (samples)
    for (int i = tid; i < 2 * HBUF; i += 256) hl[i] = (bf16_t)0.f;

    int len1 = lens[4 * g16 + quad];      // this lane's sample
    int Lmax = max(max(lens[4 * g16], lens[4 * g16 + 1]),
                   max(lens[4 * g16 + 2], lens[4 * g16 + 3]));

    float bhn0 = bhh[256 + j0];
    float bhn1 = bhh[256 + j1];

    // Whh B-fragments (pre-converted bf16), resident for all steps: 2 cols
    bf16x8 Bw[2][3][4];
#pragma unroll
    for (int c = 0; c < 2; ++c)
#pragma unroll
        for (int gate = 0; gate < 3; ++gate)
#pragma unroll
            for (int kc = 0; kc < 4; ++kc)
                Bw[c][gate][kc] = ldb8(whh_bf + ((size_t)dir * 384 + gate * 128 + (c ? j1 : j0)) * HH
                                        + kc * 32 + quad * 8);

    const bf16_t* gbase = gx3 + (size_t)(dir * 16 + g16) * TT * 1536;
    bf16_t* hb = hist2 + (size_t)(dir * 16 + g16) * TT * 512;
    int loff[6];
#pragma unroll
    for (int c = 0; c < 2; ++c)
#pragma unroll
        for (int gate = 0; gate < 3; ++gate)
            loff[c * 3 + gate] = (gate * 128 + (c ? j1 : j0)) * 4 + quad;
    int hoff0 = quad * 128 + j0;
    int hoff1 = quad * 128 + j1;
    int aoff = (col & 3) * HPAD + quad * 8;   // broadcast A-read offset

    float h0 = 0.f, h1 = 0.f;
    int S4 = (Lmax + 3) & ~3;
    bool lowquad = (quad & 1) == 0;
    bool lowhalf = (quad & 2) == 0;

    // prefetch ring, depth 4 (raw bf16 scalars; convert at consumption)
    __bf16 ring[4][6];
#pragma unroll
    for (int u = 0; u < 4; ++u) {
        int tr = dir ? (Lmax - 1 - u) : u;
        int t = min(max(tr, 0), Lmax - 1);
        size_t tb = (size_t)t * 1536;
#pragma unroll
        for (int q = 0; q < 6; ++q)
            ring[u][q] = gbase[tb + loff[q]];
    }
    lds_barrier();   // zero-init visible

    for (int sb = 0; sb < S4; sb += 4) {
#pragma unroll
        for (int u = 0; u < 4; ++u) {
            int s = sb + u;
            int tr = dir ? (Lmax - 1 - s) : s;
            int t = min(max(tr, 0), Lmax - 1);     // clamped for tail steps
            const bf16_t* hc = hl + (s & 1) * HBUF;
            bf16_t* hn = hl + ((s + 1) & 1) * HBUF;

            // consume ring slot u (loads issued 4 steps ago)
            float gx00 = (float)ring[u][0];
            float gx01 = (float)ring[u][1];
            float gx02 = (float)ring[u][2];
            float gx10 = (float)ring[u][3];
            float gx11 = (float)ring[u][4];
            float gx12 = (float)ring[u][5];

            // A fragments from LDS h (broadcast rows: sample = row & 3)
            bf16x8 a[4];
#pragma unroll
            for (int kc = 0; kc < 4; ++kc)
                a[kc] = ldb8(hc + aoff + kc * 32);

            // 12 independent 2-deep chains (split K in halves); bhn in L-half
            floatx4 crA[2], crB[2], czA[2], czB[2], cnA[2], cnB[2];
#pragma unroll
            for (int c = 0; c < 2; ++c) {
                crA[c] = (floatx4){0.f, 0.f, 0.f, 0.f};
                crB[c] = (floatx4){0.f, 0.f, 0.f, 0.f};
                czA[c] = (floatx4){0.f, 0.f, 0.f, 0.f};
                czB[c] = (floatx4){0.f, 0.f, 0.f, 0.f};
                float bh = c ? bhn1 : bhn0;
                cnA[c] = (floatx4){bh, bh, bh, bh};
                cnB[c] = (floatx4){0.f, 0.f, 0.f, 0.f};
            }
#pragma unroll
            for (int kc = 0; kc < 2; ++kc)
#pragma unroll
                for (int c = 0; c < 2; ++c) {
                    crA[c] = __builtin_amdgcn_mfma_f32_16x16x32_bf16(a[kc], Bw[c][0][kc], crA[c], 0, 0, 0);
                    czA[c] = __builtin_amdgcn_mfma_f32_16x16x32_bf16(a[kc], Bw[c][1][kc], czA[c], 0, 0, 0);
                    cnA[c] = __builtin_amdgcn_mfma_f32_16x16x32_bf16(a[kc], Bw[c][2][kc], cnA[c], 0, 0, 0);
                }
#pragma unroll
            for (int kc = 2; kc < 4; ++kc)
#pragma unroll
                for (int c = 0; c < 2; ++c) {
                    crB[c] = __builtin_amdgcn_mfma_f32_16x16x32_bf16(a[kc], Bw[c][0][kc], crB[c], 0, 0, 0);
                    czB[c] = __builtin_amdgcn_mfma_f32_16x16x32_bf16(a[kc], Bw[c][1][kc], czB[c], 0, 0, 0);
                    cnB[c] = __builtin_amdgcn_mfma_f32_16x16x32_bf16(a[kc], Bw[c][2][kc], cnB[c], 0, 0, 0);
                }

            // refill ring slot u for step s+4
            {
                int sn = s + 4;
                int trn = dir ? (Lmax - 1 - sn) : sn;
                int tn = min(max(trn, 0), Lmax - 1);
                size_t tb = (size_t)tn * 1536;
#pragma unroll
                for (int q = 0; q < 6; ++q)
                    ring[u][q] = gbase[tb + loff[q]];
            }

            bool upd = (s < Lmax) && (t < len1);

            // column 0
            float aR0 = sel4(crA[0], lowquad, lowhalf) + sel4(crB[0], lowquad, lowhalf);
            float aZ0 = sel4(czA[0], lowquad, lowhalf) + sel4(czB[0], lowquad, lowhalf);
            float aN0 = sel4(cnA[0], lowquad, lowhalf) + sel4(cnB[0], lowquad, lowhalf);
            float rg0 = sigmoid_f(aR0 + gx00);
            float zg0 = sigmoid_f(aZ0 + gx01);
            float ng0 = tanh_f(gx02 + rg0 * aN0);
            float hnew0 = ng0 + zg0 * (h0 - ng0);
            h0 = upd ? hnew0 : h0;

            // column 1
            float aR1 = sel4(crA[1], lowquad, lowhalf) + sel4(crB[1], lowquad, lowhalf);
            float aZ1 = sel4(czA[1], lowquad, lowhalf) + sel4(czB[1], lowquad, lowhalf);
            float aN1 = sel4(cnA[1], lowquad, lowhalf) + sel4(cnB[1], lowquad, lowhalf);
            float rg1 = sigmoid_f(aR1 + gx10);
            float zg1 = sigmoid_f(aZ1 + gx11);
            float ng1 = tanh_f(gx12 + rg1 * aN1);
            float hnew1 = ng1 + zg1 * (h1 - ng1);
            h1 = upd ? hnew1 : h1;

            bf16_t h16a = (bf16_t)h0;
            bf16_t h16b = (bf16_t)h1;
            hn[quad * HPAD + j0] = h16a;          // LDS row = sample
            hn[quad * HPAD + j1] = h16b;
            hb[(size_t)t * 512 + hoff0] = h16a;   // hist2 per-block region
            hb[(size_t)t * 512 + hoff1] = h16b;

            lds_barrier();   // new h visible; old buffer free
        }
    }
}

// -------- K45 (fused K4+K5): one block per sample. Per 16-t chunk (only
// t < len): scores via MFMA with M-dim = time (A rows = 16 consecutive t,
// K=256 over h_f||h_b, N=128 output channels), then in-block softmax over
// valid t and pooled = sum_t alpha[t]*Hout[b][t][:]. hist2 rows at t>=len are
// stale/poison but FINITE (0xAA bf16 = -3e-13) and masked by t<len.
__global__ __launch_bounds__(256) void k45_pool(const bf16_t* __restrict__ hist2,
                                                const bf16_t* __restrict__ wh2o_bf,
                                                const float* __restrict__ bh2o,
                                                const float* __restrict__ uw,
                                                const int* __restrict__ lens,
                                                float* __restrict__ out) {
    int b = blockIdx.x;
    int g16 = b >> 2, bl = b & 3;
    int tid = threadIdx.x;
    int lane = tid & 63, w2 = tid >> 6;       // 4 waves
    int quad = lane >> 4, col = lane & 15;
    int len = lens[b];

    __shared__ float smax[TT][4];   // per-wave partial scores, 8 KB
    __shared__ float alpha[TT];
    __shared__ float red[256];

    const bf16_t* hf = hist2 + (size_t)g16 * TT * 512 + bl * 128;        // fwd
    const bf16_t* hbk = hist2 + (size_t)(16 + g16) * TT * 512 + bl * 128; // bwd

    // this wave's 2 n-tiles (N=128 total over 4 waves)
    int n0 = (w2 * 2 + 0) * 16 + col;
    int n1 = (w2 * 2 + 1) * 16 + col;
    float bias0 = bh2o[n0], u0 = uw[n0];
    float bias1 = bh2o[n1], u1 = uw[n1];

    int nch = (len + 15) >> 4;
    for (int ch = 0; ch < nch; ++ch) {
        int t0 = ch * 16;
        int t = t0 + col;                 // A row m = t offset (t <= 511)
        bf16x8 a[8];
#pragma unroll
        for (int kc = 0; kc < 4; ++kc) {
            a[kc]     = ldb8(hf  + (size_t)t * 512 + kc * 32 + quad * 8);
            a[kc + 4] = ldb8(hbk + (size_t)t * 512 + kc * 32 + quad * 8);
        }
        float p4[4] = {0.f, 0.f, 0.f, 0.f};
#pragma unroll
        for (int tl = 0; tl < 2; ++tl) {
            int n = tl ? n1 : n0;
            float bias = tl ? bias1 : bias0;
            float u = tl ? u1 : u0;
            floatx4 acc = {0.f, 0.f, 0.f, 0.f};
#pragma unroll
            for (int kc = 0; kc < 8; ++kc) {
                bf16x8 bw = ldb8(wh2o_bf + (size_t)n * 256 + kc * 32 + quad * 8);
                acc = __builtin_amdgcn_mfma_f32_16x16x32_bf16(a[kc], bw, acc, 0, 0, 0);
            }
#pragma unroll
            for (int r = 0; r < 4; ++r)
                p4[r] += tanh_f(acc[r] + bias) * u;
        }
        // reduce over the 16 cols of this quad group (D rows = t's)
#pragma unroll
        for (int m = 1; m < 16; m <<= 1)
#pragma unroll
            for (int r = 0; r < 4; ++r)
                p4[r] += __shfl_xor(p4[r], m, 64);
        if (col == 0) {
#pragma unroll
            for (int r = 0; r < 4; ++r)
                smax[t0 + quad * 4 + r][w2] = p4[r];
        }
    }
    __syncthreads();

    // softmax over valid t
    float mx = -1e30f;
    for (int t = tid; t < TT; t += 256) {
        float s = -1e30f;
        if (t < len) s = smax[t][0] + smax[t][1] + smax[t][2] + smax[t][3];
        alpha[t] = s;
        mx = fmaxf(mx, s);
    }
    red[tid] = mx;
    __syncthreads();
    for (int s = 128; s > 0; s >>= 1) {
        if (tid < s) red[tid] = fmaxf(red[tid], red[tid + s]);
        __syncthreads();
    }
    mx = red[0];
    __syncthreads();
    float sum = 0.f;
    for (int t = tid; t < TT; t += 256) {
        float e = (t < len) ? __expf(alpha[t] - mx) : 0.f;
        alpha[t] = e;
        sum += e;
    }
    red[tid] = sum;
    __syncthreads();
    for (int s = 128; s > 0; s >>= 1) {
        if (tid < s) red[tid] += red[tid + s];
        __syncthreads();
    }
    float inv = fast_rcp(red[0]);
    __syncthreads();

    // pooled: 256 threads = 256 output channels
    int c = tid;
    int dir = c >> 7;
    int j = c & 127;
    const bf16_t* hbase = (dir ? hbk : hf) + j;
    float acc = 0.f;
    int t = 0;
    for (; t + 4 <= len; t += 4) {
        acc += alpha[t + 0] * (float)hbase[(size_t)(t + 0) * 512];
        acc += alpha[t + 1] * (float)hbase[(size_t)(t + 1) * 512];
        acc += alpha[t + 2] * (float)hbase[(size_t)(t + 2) * 512];
        acc += alpha[t + 3] * (float)hbase[(size_t)(t + 3) * 512];
    }
    for (; t < len; ++t) acc += alpha[t] * (float)hbase[(size_t)t * 512];

    out[(size_t)b * 256 + c] = acc * inv;
}

extern "C" void kernel_launch(void* const* d_in, const int* in_sizes, int n_in,
                              void* d_out, int out_size, void* d_ws, size_t ws_size,
                              hipStream_t stream) {
    const int* X       = (const int*)d_in[0];
    const int* lens    = (const int*)d_in[1];
    const float* emb   = (const float*)d_in[3];
    const float* We2i  = (const float*)d_in[4];
    const float* be2i  = (const float*)d_in[5];
    const float* Wihf  = (const float*)d_in[6];
    const float* Whhf  = (const float*)d_in[7];
    const float* bihf  = (const float*)d_in[8];
    const float* bhhf  = (const float*)d_in[9];
    const float* Wihb  = (const float*)d_in[10];
    const float* Whhb  = (const float*)d_in[11];
    const float* bihb  = (const float*)d_in[12];
    const float* bhhb  = (const float*)d_in[13];
    const float* Wh2o  = (const float*)d_in[14];
    const float* bh2o  = (const float*)d_in[15];
    const float* uw    = (const float*)d_in[16];

    char* ws = (char*)d_ws;
    size_t off = 0;
    bf16_t* we_bf = (bf16_t*)(ws + off);   off += (size_t)HH * EE * 2;          // 32 KB
    bf16_t* wih_bf = (bf16_t*)(ws + off);  off += (size_t)2 * 384 * HH * 2;     // 192 KB
    bf16_t* whh_bf = (bf16_t*)(ws + off);  off += (size_t)2 * 384 * HH * 2;     // 192 KB
    bf16_t* wh2o_bf = (bf16_t*)(ws + off); off += (size_t)OO * 256 * 2;         // 64 KB
    float* gxbias = (float*)(ws + off);    off += 768 * 4;                      // 3 KB
    off = (off + 255) & ~(size_t)255;
    bf16_t* gx3 = (bf16_t*)(ws + off);     off += (size_t)32 * TT * 384 * 4 * 2; // 50.3 MB
    bf16_t* hist2 = (bf16_t*)(ws + off);   off += (size_t)32 * TT * 4 * 128 * 2; // 16.8 MB

    float* out = (float*)d_out;

    k0_conv<<<dim3(256), dim3(256), 0, stream>>>(We2i, Wihf, Wihb, Whhf, Whhb,
                                                 Wh2o, bihf, bhhf, bihb, bhhb,
                                                 we_bf, wih_bf, whh_bf, wh2o_bf, gxbias);
    k12_gx<<<dim3(TT), dim3(256), 0, stream>>>(X, emb, we_bf, be2i, wih_bf, gxbias, lens, gx3);
    k3_gru<<<dim3(16, 2), dim3(256), 0, stream>>>(gx3, whh_bf, bhhf, bhhb, lens, hist2);
    k45_pool<<<dim3(BB), dim3(256), 0, stream>>>(hist2, wh2o_bf, bh2o, uw, lens, out);
}

// Round 2
// 428.015 us; speedup vs baseline: 1.1163x; 1.1163x over previous
//
#include <hip/hip_runtime.h>
#include <hip/hip_bf16.h>

// Shapes (fixed by the problem)
#define VV 50000
#define EE 128
#define HH 128
#define OO 128
#define BB 64
#define TT 512

typedef __bf16 bf16_t;
typedef __attribute__((ext_vector_type(8))) __bf16 bf16x8;
typedef __attribute__((ext_vector_type(4))) __bf16 bf16x4;
typedef __attribute__((ext_vector_type(4))) float floatx4;

// exp2-prescale constants: sigmoid/tanh computed via v_exp_f32 (=2^x) with
// log2e folded into the r/z/n weight rows in k0 (r,z: -log2e; n: +2*log2e).
#define SC_RZ (-1.4426950408889634f)
#define SC_N  (2.8853900817779268f)

__device__ __forceinline__ bf16x8 ldb8(const bf16_t* p) {
    return *reinterpret_cast<const bf16x8*>(p);
}

// load 8 consecutive fp32, round to bf16 fragment (two float4 loads)
__device__ __forceinline__ bf16x8 ldf8_bf(const float* p) {
    const float4* q = reinterpret_cast<const float4*>(p);
    float4 u = q[0], v = q[1];
    bf16x8 r;
    r[0] = (__bf16)u.x; r[1] = (__bf16)u.y; r[2] = (__bf16)u.z; r[3] = (__bf16)u.w;
    r[4] = (__bf16)v.x; r[5] = (__bf16)v.y; r[6] = (__bf16)v.z; r[7] = (__bf16)v.w;
    return r;
}

__device__ __forceinline__ float fast_rcp(float x) { return __builtin_amdgcn_rcpf(x); }
__device__ __forceinline__ float exp2_f(float x) { return __builtin_amdgcn_exp2f(x); }
__device__ __forceinline__ float tanh_f(float x) {
    float e = __expf(2.0f * x);
    return 1.0f - 2.0f * fast_rcp(e + 1.0f);
}

// LDS-only barrier: wait LDS ops, sync — do NOT drain vmcnt (hist stores and
// gx ring-prefetch loads stay in flight across steps).
__device__ __forceinline__ void lds_barrier() {
    asm volatile("s_waitcnt lgkmcnt(0)\n\ts_barrier" ::: "memory");
}

// select D-reg by quad (D row = quad*4 + r -> sample = r; picking r = quad
// gives row 5*quad -> sample quad since 5 == 1 mod 4)
__device__ __forceinline__ float sel4(floatx4 v, bool lowquad, bool lowhalf) {
    return lowhalf ? (lowquad ? v[0] : v[1]) : (lowquad ? v[2] : v[3]);
}

// -------- K0: preconvert small weights fp32->bf16 + fold gx bias.
// NEW: fold exp2 scaling into Wih/Whh rows and biases (see SC_RZ/SC_N).
__global__ __launch_bounds__(256) void k0_conv(
    const float* __restrict__ we,
    const float* __restrict__ wihf, const float* __restrict__ wihb,
    const float* __restrict__ whhf, const float* __restrict__ whhb,
    const float* __restrict__ wh2o,
    const float* __restrict__ bihf, const float* __restrict__ bhhf,
    const float* __restrict__ bihb, const float* __restrict__ bhhb,
    bf16_t* __restrict__ we_bf,
    bf16_t* __restrict__ wih_bf, bf16_t* __restrict__ whh_bf,
    bf16_t* __restrict__ wh2o_bf, float* __restrict__ gxbias) {
    int tid = blockIdx.x * 256 + threadIdx.x;
    int np = gridDim.x * 256;
    for (int i = tid; i < HH * EE; i += np) we_bf[i] = (bf16_t)we[i];
    for (int i = tid; i < 384 * HH; i += np) {
        int nrow = i >> 7;                      // row over 384 (HH=128 cols)
        float sc = (nrow < 256) ? SC_RZ : SC_N;
        wih_bf[i] = (bf16_t)(sc * wihf[i]);
        wih_bf[384 * HH + i] = (bf16_t)(sc * wihb[i]);
        whh_bf[i] = (bf16_t)(sc * whhf[i]);
        whh_bf[384 * HH + i] = (bf16_t)(sc * whhb[i]);
    }
    for (int i = tid; i < OO * 256; i += np) wh2o_bf[i] = (bf16_t)wh2o[i];
    if (tid < 768) {
        int dir = tid / 384, n = tid % 384;
        const float* bih = dir ? bihb : bihf;
        const float* bhh = dir ? bhhb : bhhf;
        float sc = (n < 256) ? SC_RZ : SC_N;
        gxbias[tid] = sc * bih[n] + (n < 256 ? sc * bhh[n] : 0.0f);  // bhh_n goes in K3's C-init
    }
}

// -------- K12 (fused K1+K2), 4 timesteps per block, with dead-time skip:
// lens sorted descending -> tile g's max len = lens[16g]; blocks entirely past
// it produce gx no one reads (K3 stops at its group Lmax <= lens[16g]).
__global__ __launch_bounds__(256) void k12_gx(const int* __restrict__ X,
                                              const float* __restrict__ emb,
                                              const bf16_t* __restrict__ we_bf,
                                              const float* __restrict__ be,
                                              const bf16_t* __restrict__ wih_bf,
                                              const float* __restrict__ gxbias,
                                              const int* __restrict__ lens,
                                              bf16_t* __restrict__ gx3) {
    int blk = blockIdx.x;            // 0..511 = tq*4 + g
    int tq = blk >> 2;
    int g = blk & 3;                 // 16-sample tile
    if (4 * tq >= lens[16 * g]) return;   // uniform: whole block dead

    int lane = threadIdx.x & 63;
    int w2 = threadIdx.x >> 6;       // wave 0..3
    int quad = lane >> 4, col = lane & 15;

    __shared__ bf16_t xs[4][16 * 136];   // 4 xh tiles, row-padded

    // stage 1 x4: xh = emb[X] @ We^T + be (A rows = 16 samples at t=4tq+tt)
#pragma unroll
    for (int tt = 0; tt < 4; ++tt) {
        int t = 4 * tq + tt;
        int v = X[(g * 16 + col) * TT + t];
        bf16x8 a[4];
#pragma unroll
        for (int kc = 0; kc < 4; ++kc)
            a[kc] = ldf8_bf(emb + (size_t)v * EE + kc * 32 + quad * 8);
#pragma unroll
        for (int tl = 0; tl < 2; ++tl) {
            int n = 32 * w2 + 16 * tl + col;
            floatx4 acc = {0.f, 0.f, 0.f, 0.f};
#pragma unroll
            for (int kc = 0; kc < 4; ++kc) {
                bf16x8 bw = ldb8(we_bf + (size_t)n * EE + kc * 32 + quad * 8);
                acc = __builtin_amdgcn_mfma_f32_16x16x32_bf16(a[kc], bw, acc, 0, 0, 0);
            }
            float bias = be[n];
#pragma unroll
            for (int r = 0; r < 4; ++r)
                xs[tt][(quad * 4 + r) * 136 + n] = (bf16_t)(acc[r] + bias);
        }
    }
    __syncthreads();

    // stage 2: gx = xh @ Wih^T + gxbias, both dirs; Wih loaded once per n-tile
    bf16x8 a2[4][4];
#pragma unroll
    for (int tt = 0; tt < 4; ++tt)
#pragma unroll
        for (int kc = 0; kc < 4; ++kc)
            a2[tt][kc] = ldb8(xs[tt] + col * 136 + kc * 32 + quad * 8);

#pragma unroll
    for (int tl = 0; tl < 12; ++tl) {
        int idx = w2 * 12 + tl;          // 0..47
        int dir = idx >= 24;
        int n = (idx - dir * 24) * 16 + col;   // 0..383
        bf16x8 bw[4];
#pragma unroll
        for (int kc = 0; kc < 4; ++kc)
            bw[kc] = ldb8(wih_bf + ((size_t)dir * 384 + n) * HH + kc * 32 + quad * 8);
        float bias = gxbias[dir * 384 + n];
#pragma unroll
        for (int tt = 0; tt < 4; ++tt) {
            int t = 4 * tq + tt;
            floatx4 acc = {0.f, 0.f, 0.f, 0.f};
#pragma unroll
            for (int kc = 0; kc < 4; ++kc)
                acc = __builtin_amdgcn_mfma_f32_16x16x32_bf16(a2[tt][kc], bw[kc], acc, 0, 0, 0);
            bf16x4 pack;
#pragma unroll
            for (int r = 0; r < 4; ++r)
                pack[r] = (__bf16)(acc[r] + bias);   // D row r -> sample 16g+quad*4+r
            *reinterpret_cast<bf16x4*>(
                gx3 + (((size_t)(dir * 16 + 4 * g + quad) * TT + t) * 384 + n) * 4) = pack;
        }
    }
}

// -------- K3: masked GRU recurrence (8-wave R9 structure, reverted from the
// failed 4-wave experiment — 2 co-resident waves/SIMD are what hides the
// per-step latency chain). This round shortens the chain itself:
//  (a) K=128 accumulation as 2 independent 2-deep MFMA chains per gate,
//  (b) exp2-prescaled weights -> gate math is raw v_exp_f32 (no neg/scale),
//  (c) chain order r -> n -> z with gx0/gx1 folded into MFMA C-init so the
//      r-sigmoid starts while z-gate MFMAs are still in flight.
#define HPAD 144
#define HBUF (4 * HPAD)
__global__ __launch_bounds__(512) void k3_gru(const bf16_t* __restrict__ gx3,
                                              const bf16_t* __restrict__ whh_bf,
                                              const float* __restrict__ bhh_f,
                                              const float* __restrict__ bhh_b,
                                              const int* __restrict__ lens,
                                              bf16_t* __restrict__ hist2) {
    int g16 = blockIdx.x;    // 4-sample group: samples 4*g16 .. 4*g16+3
    int dir = blockIdx.y;
    const float* bhh = dir ? bhh_b : bhh_f;

    int tid = threadIdx.x;
    int w = tid >> 6;        // wave 0..7
    int lane = tid & 63;
    int quad = lane >> 4, col = lane & 15;
    int j = 16 * w + col;    // owned hidden column

    __shared__ bf16_t hl[2 * HBUF];   // double-buffered h, 4 rows (samples)
    for (int i = tid; i < 2 * HBUF; i += 512) hl[i] = (bf16_t)0.f;

    int len1 = lens[4 * g16 + quad];      // this lane's sample
    int Lmax = max(max(lens[4 * g16], lens[4 * g16 + 1]),
                   max(lens[4 * g16 + 2], lens[4 * g16 + 3]));

    float bhn = SC_N * bhh[256 + j];      // n-row scale applied (C-init)

    // Whh B-fragments (pre-converted bf16, pre-scaled), resident for all steps
    bf16x8 Bw[3][4];
#pragma unroll
    for (int gate = 0; gate < 3; ++gate)
#pragma unroll
        for (int kc = 0; kc < 4; ++kc)
            Bw[gate][kc] = ldb8(whh_bf + ((size_t)dir * 384 + gate * 128 + j) * HH + kc * 32 + quad * 8);

    const bf16_t* gbase = gx3 + (size_t)(dir * 16 + g16) * TT * 1536;
    bf16_t* hb = hist2 + (size_t)(dir * 16 + g16) * TT * 512;
    int loff[3];
#pragma unroll
    for (int gate = 0; gate < 3; ++gate)
        loff[gate] = (gate * 128 + j) * 4 + quad;
    int hoff = quad * 128 + j;
    int aoff = (col & 3) * HPAD + quad * 8;   // broadcast A-read offset

    float h = 0.f;
    int S4 = (Lmax + 3) & ~3;
    bool lowquad = (quad & 1) == 0;
    bool lowhalf = (quad & 2) == 0;

    // prefetch ring, depth 4 (raw bf16 scalars; convert at consumption)
    __bf16 ring[4][3];
#pragma unroll
    for (int u = 0; u < 4; ++u) {
        int tr = dir ? (Lmax - 1 - u) : u;
        int t = min(max(tr, 0), Lmax - 1);
#pragma unroll
        for (int gate = 0; gate < 3; ++gate)
            ring[u][gate] = gbase[(size_t)t * 1536 + loff[gate]];
    }
    lds_barrier();   // zero-init visible

    for (int sb = 0; sb < S4; sb += 4) {
#pragma unroll
        for (int u = 0; u < 4; ++u) {
            int s = sb + u;
            int tr = dir ? (Lmax - 1 - s) : s;
            int t = min(max(tr, 0), Lmax - 1);     // clamped for tail steps
            const bf16_t* hc = hl + (s & 1) * HBUF;
            bf16_t* hn = hl + ((s + 1) & 1) * HBUF;

            // consume ring slot u (loads issued 4 steps ago)
            float gx0 = (float)ring[u][0];   // -log2e * (x-gate r input)
            float gx1 = (float)ring[u][1];   // -log2e * (x-gate z input)
            float gx2 = (float)ring[u][2];   // 2log2e * (x-gate n input)

            // A fragments from LDS h (broadcast rows: sample = row & 3)
            bf16x8 a[4];
#pragma unroll
            for (int kc = 0; kc < 4; ++kc)
                a[kc] = ldb8(hc + aoff + kc * 32);

            // 6 independent 2-deep chains; gx0/gx1/bhn folded into C-init.
            // Order r -> n -> z so rg's transcendental chain overlaps z MFMAs.
            floatx4 crA = {gx0, gx0, gx0, gx0};
            floatx4 crB = {0.f, 0.f, 0.f, 0.f};
            floatx4 cnA = {bhn, bhn, bhn, bhn};
            floatx4 cnB = {0.f, 0.f, 0.f, 0.f};
            floatx4 czA = {gx1, gx1, gx1, gx1};
            floatx4 czB = {0.f, 0.f, 0.f, 0.f};
            crA = __builtin_amdgcn_mfma_f32_16x16x32_bf16(a[0], Bw[0][0], crA, 0, 0, 0);
            crB = __builtin_amdgcn_mfma_f32_16x16x32_bf16(a[2], Bw[0][2], crB, 0, 0, 0);
            crA = __builtin_amdgcn_mfma_f32_16x16x32_bf16(a[1], Bw[0][1], crA, 0, 0, 0);
            crB = __builtin_amdgcn_mfma_f32_16x16x32_bf16(a[3], Bw[0][3], crB, 0, 0, 0);
            cnA = __builtin_amdgcn_mfma_f32_16x16x32_bf16(a[0], Bw[2][0], cnA, 0, 0, 0);
            cnB = __builtin_amdgcn_mfma_f32_16x16x32_bf16(a[2], Bw[2][2], cnB, 0, 0, 0);
            cnA = __builtin_amdgcn_mfma_f32_16x16x32_bf16(a[1], Bw[2][1], cnA, 0, 0, 0);
            cnB = __builtin_amdgcn_mfma_f32_16x16x32_bf16(a[3], Bw[2][3], cnB, 0, 0, 0);
            czA = __builtin_amdgcn_mfma_f32_16x16x32_bf16(a[0], Bw[1][0], czA, 0, 0, 0);
            czB = __builtin_amdgcn_mfma_f32_16x16x32_bf16(a[2], Bw[1][2], czB, 0, 0, 0);
            czA = __builtin_amdgcn_mfma_f32_16x16x32_bf16(a[1], Bw[1][1], czA, 0, 0, 0);
            czB = __builtin_amdgcn_mfma_f32_16x16x32_bf16(a[3], Bw[1][3], czB, 0, 0, 0);

            // refill ring slot u for step s+4 (fills MFMA shadow)
            {
                int sn = s + 4;
                int trn = dir ? (Lmax - 1 - sn) : sn;
                int tn = min(max(trn, 0), Lmax - 1);
#pragma unroll
                for (int gate = 0; gate < 3; ++gate)
                    ring[u][gate] = gbase[(size_t)tn * 1536 + loff[gate]];
            }

            // register select: reg r = gates of sample r (D-row periodicity);
            // this lane's sample is quad -> pick reg[quad]. No cross-lane ops.
            float aR = sel4(crA, lowquad, lowhalf) + sel4(crB, lowquad, lowhalf);
            float rg = fast_rcp(1.0f + exp2_f(aR));          // sigmoid (prescaled)
            float aN = sel4(cnA, lowquad, lowhalf) + sel4(cnB, lowquad, lowhalf);
            float v  = fmaf(rg, aN, gx2);                    // 2log2e * tanh-arg
            float ng = fmaf(-2.0f, fast_rcp(exp2_f(v) + 1.0f), 1.0f);  // tanh
            float aZ = sel4(czA, lowquad, lowhalf) + sel4(czB, lowquad, lowhalf);
            float zg = fast_rcp(1.0f + exp2_f(aZ));          // sigmoid (prescaled)
            float hnew = fmaf(zg, h - ng, ng);               // (1-z)n + z*h

            bool upd = (s < Lmax) && (t < len1);
            h = upd ? hnew : h;
            bf16_t h16 = (bf16_t)h;
            hn[quad * HPAD + j] = h16;            // LDS row = sample
            hb[(size_t)t * 512 + hoff] = h16;     // hist2 per-block region

            lds_barrier();   // new h visible; old buffer free
        }
    }
}

// -------- K45 (fused K4+K5): one block per sample. Per 16-t chunk (only
// t < len): scores via MFMA with M-dim = time (A rows = 16 consecutive t,
// K=256 over h_f||h_b, N=128 output channels), then in-block softmax over
// valid t and pooled = sum_t alpha[t]*Hout[b][t][:]. hist2 rows at t>=len are
// stale/poison but FINITE (0xAA bf16 = -3e-13) and masked by t<len.
__global__ __launch_bounds__(256) void k45_pool(const bf16_t* __restrict__ hist2,
                                                const bf16_t* __restrict__ wh2o_bf,
                                                const float* __restrict__ bh2o,
                                                const float* __restrict__ uw,
                                                const int* __restrict__ lens,
                                                float* __restrict__ out) {
    int b = blockIdx.x;
    int g16 = b >> 2, bl = b & 3;
    int tid = threadIdx.x;
    int lane = tid & 63, w2 = tid >> 6;       // 4 waves
    int quad = lane >> 4, col = lane & 15;
    int len = lens[b];

    __shared__ float smax[TT][4];   // per-wave partial scores, 8 KB
    __shared__ float alpha[TT];
    __shared__ float red[256];

    const bf16_t* hf = hist2 + (size_t)g16 * TT * 512 + bl * 128;        // fwd
    const bf16_t* hbk = hist2 + (size_t)(16 + g16) * TT * 512 + bl * 128; // bwd

    // this wave's 2 n-tiles (N=128 total over 4 waves)
    int n0 = (w2 * 2 + 0) * 16 + col;
    int n1 = (w2 * 2 + 1) * 16 + col;
    float bias0 = bh2o[n0], u0 = uw[n0];
    float bias1 = bh2o[n1], u1 = uw[n1];

    int nch = (len + 15) >> 4;
    for (int ch = 0; ch < nch; ++ch) {
        int t0 = ch * 16;
        int t = t0 + col;                 // A row m = t offset (t <= 511)
        bf16x8 a[8];
#pragma unroll
        for (int kc = 0; kc < 4; ++kc) {
            a[kc]     = ldb8(hf  + (size_t)t * 512 + kc * 32 + quad * 8);
            a[kc + 4] = ldb8(hbk + (size_t)t * 512 + kc * 32 + quad * 8);
        }
        float p4[4] = {0.f, 0.f, 0.f, 0.f};
#pragma unroll
        for (int tl = 0; tl < 2; ++tl) {
            int n = tl ? n1 : n0;
            float bias = tl ? bias1 : bias0;
            float u = tl ? u1 : u0;
            floatx4 acc = {0.f, 0.f, 0.f, 0.f};
#pragma unroll
            for (int kc = 0; kc < 8; ++kc) {
                bf16x8 bw = ldb8(wh2o_bf + (size_t)n * 256 + kc * 32 + quad * 8);
                acc = __builtin_amdgcn_mfma_f32_16x16x32_bf16(a[kc], bw, acc, 0, 0, 0);
            }
#pragma unroll
            for (int r = 0; r < 4; ++r)
                p4[r] += tanh_f(acc[r] + bias) * u;
        }
        // reduce over the 16 cols of this quad group (D rows = t's)
#pragma unroll
        for (int m = 1; m < 16; m <<= 1)
#pragma unroll
            for (int r = 0; r < 4; ++r)
                p4[r] += __shfl_xor(p4[r], m, 64);
        if (col == 0) {
#pragma unroll
            for (int r = 0; r < 4; ++r)
                smax[t0 + quad * 4 + r][w2] = p4[r];
        }
    }
    __syncthreads();

    // softmax over valid t
    float mx = -1e30f;
    for (int t = tid; t < TT; t += 256) {
        float s = -1e30f;
        if (t < len) s = smax[t][0] + smax[t][1] + smax[t][2] + smax[t][3];
        alpha[t] = s;
        mx = fmaxf(mx, s);
    }
    red[tid] = mx;
    __syncthreads();
    for (int s = 128; s > 0; s >>= 1) {
        if (tid < s) red[tid] = fmaxf(red[tid], red[tid + s]);
        __syncthreads();
    }
    mx = red[0];
    __syncthreads();
    float sum = 0.f;
    for (int t = tid; t < TT; t += 256) {
        float e = (t < len) ? __expf(alpha[t] - mx) : 0.f;
        alpha[t] = e;
        sum += e;
    }
    red[tid] = sum;
    __syncthreads();
    for (int s = 128; s > 0; s >>= 1) {
        if (tid < s) red[tid] += red[tid + s];
        __syncthreads();
    }
    float inv = fast_rcp(red[0]);
    __syncthreads();

    // pooled: 256 threads = 256 output channels
    int c = tid;
    int dir = c >> 7;
    int j = c & 127;
    const bf16_t* hbase = (dir ? hbk : hf) + j;
    float acc = 0.f;
    int t = 0;
    for (; t + 4 <= len; t += 4) {
        acc += alpha[t + 0] * (float)hbase[(size_t)(t + 0) * 512];
        acc += alpha[t + 1] * (float)hbase[(size_t)(t + 1) * 512];
        acc += alpha[t + 2] * (float)hbase[(size_t)(t + 2) * 512];
        acc += alpha[t + 3] * (float)hbase[(size_t)(t + 3) * 512];
    }
    for (; t < len; ++t) acc += alpha[t] * (float)hbase[(size_t)t * 512];

    out[(size_t)b * 256 + c] = acc * inv;
}

extern "C" void kernel_launch(void* const* d_in, const int* in_sizes, int n_in,
                              void* d_out, int out_size, void* d_ws, size_t ws_size,
                              hipStream_t stream) {
    const int* X       = (const int*)d_in[0];
    const int* lens    = (const int*)d_in[1];
    const float* emb   = (const float*)d_in[3];
    const float* We2i  = (const float*)d_in[4];
    const float* be2i  = (const float*)d_in[5];
    const float* Wihf  = (const float*)d_in[6];
    const float* Whhf  = (const float*)d_in[7];
    const float* bihf  = (const float*)d_in[8];
    const float* bhhf  = (const float*)d_in[9];
    const float* Wihb  = (const float*)d_in[10];
    const float* Whhb  = (const float*)d_in[11];
    const float* bihb  = (const float*)d_in[12];
    const float* bhhb  = (const float*)d_in[13];
    const float* Wh2o  = (const float*)d_in[14];
    const float* bh2o  = (const float*)d_in[15];
    const float* uw    = (const float*)d_in[16];

    char* ws = (char*)d_ws;
    size_t off = 0;
    bf16_t* we_bf = (bf16_t*)(ws + off);   off += (size_t)HH * EE * 2;          // 32 KB
    bf16_t* wih_bf = (bf16_t*)(ws + off);  off += (size_t)2 * 384 * HH * 2;     // 192 KB
    bf16_t* whh_bf = (bf16_t*)(ws + off);  off += (size_t)2 * 384 * HH * 2;     // 192 KB
    bf16_t* wh2o_bf = (bf16_t*)(ws + off); off += (size_t)OO * 256 * 2;         // 64 KB
    float* gxbias = (float*)(ws + off);    off += 768 * 4;                      // 3 KB
    off = (off + 255) & ~(size_t)255;
    bf16_t* gx3 = (bf16_t*)(ws + off);     off += (size_t)32 * TT * 384 * 4 * 2; // 50.3 MB
    bf16_t* hist2 = (bf16_t*)(ws + off);   off += (size_t)32 * TT * 4 * 128 * 2; // 16.8 MB

    float* out = (float*)d_out;

    k0_conv<<<dim3(256), dim3(256), 0, stream>>>(We2i, Wihf, Wihb, Whhf, Whhb,
                                                 Wh2o, bihf, bhhf, bihb, bhhb,
                                                 we_bf, wih_bf, whh_bf, wh2o_bf, gxbias);
    k12_gx<<<dim3(TT), dim3(256), 0, stream>>>(X, emb, we_bf, be2i, wih_bf, gxbias, lens, gx3);
    k3_gru<<<dim3(16, 2), dim3(512), 0, stream>>>(gx3, whh_bf, bhhf, bhhb, lens, hist2);
    k45_pool<<<dim3(BB), dim3(256), 0, stream>>>(hist2, wh2o_bf, bh2o, uw, lens, out);
}

// Round 3
// 387.184 us; speedup vs baseline: 1.2341x; 1.1055x over previous
//
#include <hip/hip_runtime.h>
#include <hip/hip_bf16.h>

// Shapes (fixed by the problem)
#define VV 50000
#define EE 128
#define HH 128
#define OO 128
#define BB 64
#define TT 512

typedef __bf16 bf16_t;
typedef __attribute__((ext_vector_type(8))) __bf16 bf16x8;
typedef __attribute__((ext_vector_type(4))) __bf16 bf16x4;
typedef __attribute__((ext_vector_type(4))) float floatx4;

// exp2-prescale constants: sigmoid/tanh computed via v_exp_f32 (=2^x) with
// log2e folded into the r/z/n weight rows in k0 (r,z: -log2e; n: +2*log2e).
#define SC_RZ (-1.4426950408889634f)
#define SC_N  (2.8853900817779268f)

__device__ __forceinline__ bf16x8 ldb8(const bf16_t* p) {
    return *reinterpret_cast<const bf16x8*>(p);
}

// load 8 consecutive fp32, round to bf16 fragment (two float4 loads)
__device__ __forceinline__ bf16x8 ldf8_bf(const float* p) {
    const float4* q = reinterpret_cast<const float4*>(p);
    float4 u = q[0], v = q[1];
    bf16x8 r;
    r[0] = (__bf16)u.x; r[1] = (__bf16)u.y; r[2] = (__bf16)u.z; r[3] = (__bf16)u.w;
    r[4] = (__bf16)v.x; r[5] = (__bf16)v.y; r[6] = (__bf16)v.z; r[7] = (__bf16)v.w;
    return r;
}

__device__ __forceinline__ float fast_rcp(float x) { return __builtin_amdgcn_rcpf(x); }
__device__ __forceinline__ float exp2_f(float x) { return __builtin_amdgcn_exp2f(x); }
__device__ __forceinline__ float tanh_f(float x) {
    float e = __expf(2.0f * x);
    return 1.0f - 2.0f * fast_rcp(e + 1.0f);
}

// LDS-only barrier: wait LDS ops, sync — do NOT drain vmcnt (hist stores and
// gx ring-prefetch loads stay in flight across steps).
__device__ __forceinline__ void lds_barrier() {
    asm volatile("s_waitcnt lgkmcnt(0)\n\ts_barrier" ::: "memory");
}

// -------- K0: preconvert small weights fp32->bf16 + fold gx bias.
// exp2 scaling folded into Wih/Whh rows and biases (see SC_RZ/SC_N).
__global__ __launch_bounds__(256) void k0_conv(
    const float* __restrict__ we,
    const float* __restrict__ wihf, const float* __restrict__ wihb,
    const float* __restrict__ whhf, const float* __restrict__ whhb,
    const float* __restrict__ wh2o,
    const float* __restrict__ bihf, const float* __restrict__ bhhf,
    const float* __restrict__ bihb, const float* __restrict__ bhhb,
    bf16_t* __restrict__ we_bf,
    bf16_t* __restrict__ wih_bf, bf16_t* __restrict__ whh_bf,
    bf16_t* __restrict__ wh2o_bf, float* __restrict__ gxbias) {
    int tid = blockIdx.x * 256 + threadIdx.x;
    int np = gridDim.x * 256;
    for (int i = tid; i < HH * EE; i += np) we_bf[i] = (bf16_t)we[i];
    for (int i = tid; i < 384 * HH; i += np) {
        int nrow = i >> 7;                      // row over 384 (HH=128 cols)
        float sc = (nrow < 256) ? SC_RZ : SC_N;
        wih_bf[i] = (bf16_t)(sc * wihf[i]);
        wih_bf[384 * HH + i] = (bf16_t)(sc * wihb[i]);
        whh_bf[i] = (bf16_t)(sc * whhf[i]);
        whh_bf[384 * HH + i] = (bf16_t)(sc * whhb[i]);
    }
    for (int i = tid; i < OO * 256; i += np) wh2o_bf[i] = (bf16_t)wh2o[i];
    if (tid < 768) {
        int dir = tid / 384, n = tid % 384;
        const float* bih = dir ? bihb : bihf;
        const float* bhh = dir ? bhhb : bhhf;
        float sc = (n < 256) ? SC_RZ : SC_N;
        gxbias[tid] = sc * bih[n] + (n < 256 ? sc * bhh[n] : 0.0f);  // bhh_n goes in K3's C-init
    }
}

// -------- K12 (fused K1+K2), 4 timesteps per block, with dead-time skip:
// lens sorted descending -> tile g's max len = lens[16g]; blocks entirely past
// it produce gx no one reads (K3 stops at its group Lmax <= lens[16g]).
__global__ __launch_bounds__(256) void k12_gx(const int* __restrict__ X,
                                              const float* __restrict__ emb,
                                              const bf16_t* __restrict__ we_bf,
                                              const float* __restrict__ be,
                                              const bf16_t* __restrict__ wih_bf,
                                              const float* __restrict__ gxbias,
                                              const int* __restrict__ lens,
                                              bf16_t* __restrict__ gx3) {
    int blk = blockIdx.x;            // 0..511 = tq*4 + g
    int tq = blk >> 2;
    int g = blk & 3;                 // 16-sample tile
    if (4 * tq >= lens[16 * g]) return;   // uniform: whole block dead

    int lane = threadIdx.x & 63;
    int w2 = threadIdx.x >> 6;       // wave 0..3
    int quad = lane >> 4, col = lane & 15;

    __shared__ bf16_t xs[4][16 * 136];   // 4 xh tiles, row-padded

    // stage 1 x4: xh = emb[X] @ We^T + be (A rows = 16 samples at t=4tq+tt)
#pragma unroll
    for (int tt = 0; tt < 4; ++tt) {
        int t = 4 * tq + tt;
        int v = X[(g * 16 + col) * TT + t];
        bf16x8 a[4];
#pragma unroll
        for (int kc = 0; kc < 4; ++kc)
            a[kc] = ldf8_bf(emb + (size_t)v * EE + kc * 32 + quad * 8);
#pragma unroll
        for (int tl = 0; tl < 2; ++tl) {
            int n = 32 * w2 + 16 * tl + col;
            floatx4 acc = {0.f, 0.f, 0.f, 0.f};
#pragma unroll
            for (int kc = 0; kc < 4; ++kc) {
                bf16x8 bw = ldb8(we_bf + (size_t)n * EE + kc * 32 + quad * 8);
                acc = __builtin_amdgcn_mfma_f32_16x16x32_bf16(a[kc], bw, acc, 0, 0, 0);
            }
            float bias = be[n];
#pragma unroll
            for (int r = 0; r < 4; ++r)
                xs[tt][(quad * 4 + r) * 136 + n] = (bf16_t)(acc[r] + bias);
        }
    }
    __syncthreads();

    // stage 2: gx = xh @ Wih^T + gxbias, both dirs; Wih loaded once per n-tile
    bf16x8 a2[4][4];
#pragma unroll
    for (int tt = 0; tt < 4; ++tt)
#pragma unroll
        for (int kc = 0; kc < 4; ++kc)
            a2[tt][kc] = ldb8(xs[tt] + col * 136 + kc * 32 + quad * 8);

#pragma unroll
    for (int tl = 0; tl < 12; ++tl) {
        int idx = w2 * 12 + tl;          // 0..47
        int dir = idx >= 24;
        int n = (idx - dir * 24) * 16 + col;   // 0..383
        bf16x8 bw[4];
#pragma unroll
        for (int kc = 0; kc < 4; ++kc)
            bw[kc] = ldb8(wih_bf + ((size_t)dir * 384 + n) * HH + kc * 32 + quad * 8);
        float bias = gxbias[dir * 384 + n];
#pragma unroll
        for (int tt = 0; tt < 4; ++tt) {
            int t = 4 * tq + tt;
            floatx4 acc = {0.f, 0.f, 0.f, 0.f};
#pragma unroll
            for (int kc = 0; kc < 4; ++kc)
                acc = __builtin_amdgcn_mfma_f32_16x16x32_bf16(a2[tt][kc], bw[kc], acc, 0, 0, 0);
            bf16x4 pack;
#pragma unroll
            for (int r = 0; r < 4; ++r)
                pack[r] = (__bf16)(acc[r] + bias);   // D row r -> sample 16g+quad*4+r
            *reinterpret_cast<bf16x4*>(
                gx3 + (((size_t)(dir * 16 + 4 * g + quad) * TT + t) * 384 + n) * 4) = pack;
        }
    }
}

// -------- K3: masked GRU recurrence — EXACT R0 structure (203 us measured):
// 8 waves, 3 chains x 4-deep compiler-scheduled MFMA, ring prefetch.
// Two hazard-free diffs only:
//  (1) A-layout row = col>>2 (h[sample col>>2]): all 4 D-regs in a lane's
//      quad hold sample=quad -> use cr[0] directly, no cndmask selects.
//      Identical LDS address set (same banks/broadcast), different lanes.
//  (2) exp2-prescaled weights (k0) -> gate tail is raw v_exp_f32, no muls.
#define HPAD 144
#define HBUF (4 * HPAD)
__global__ __launch_bounds__(512) void k3_gru(const bf16_t* __restrict__ gx3,
                                              const bf16_t* __restrict__ whh_bf,
                                              const float* __restrict__ bhh_f,
                                              const float* __restrict__ bhh_b,
                                              const int* __restrict__ lens,
                                              bf16_t* __restrict__ hist2) {
    int g16 = blockIdx.x;    // 4-sample group: samples 4*g16 .. 4*g16+3
    int dir = blockIdx.y;
    const float* bhh = dir ? bhh_b : bhh_f;

    int tid = threadIdx.x;
    int w = tid >> 6;        // wave 0..7
    int lane = tid & 63;
    int quad = lane >> 4, col = lane & 15;
    int j = 16 * w + col;    // owned hidden column

    __shared__ bf16_t hl[2 * HBUF];   // double-buffered h, 4 rows (samples)
    for (int i = tid; i < 2 * HBUF; i += 512) hl[i] = (bf16_t)0.f;

    int len1 = lens[4 * g16 + quad];      // this lane's sample
    int Lmax = max(max(lens[4 * g16], lens[4 * g16 + 1]),
                   max(lens[4 * g16 + 2], lens[4 * g16 + 3]));

    float bhn = SC_N * bhh[256 + j];      // n-row scale applied (C-init)

    // Whh B-fragments (pre-converted bf16, pre-scaled), resident for all steps
    bf16x8 Bw[3][4];
#pragma unroll
    for (int gate = 0; gate < 3; ++gate)
#pragma unroll
        for (int kc = 0; kc < 4; ++kc)
            Bw[gate][kc] = ldb8(whh_bf + ((size_t)dir * 384 + gate * 128 + j) * HH + kc * 32 + quad * 8);

    const bf16_t* gbase = gx3 + (size_t)(dir * 16 + g16) * TT * 1536;
    bf16_t* hb = hist2 + (size_t)(dir * 16 + g16) * TT * 512;
    int loff[3];
#pragma unroll
    for (int gate = 0; gate < 3; ++gate)
        loff[gate] = (gate * 128 + j) * 4 + quad;
    int hoff = quad * 128 + j;
    int aoff = (col >> 2) * HPAD + quad * 8;   // broadcast A-read: row m -> sample m>>2

    float h = 0.f;
    int S4 = (Lmax + 3) & ~3;

    // prefetch ring, depth 4 (raw bf16 scalars; convert at consumption)
    __bf16 ring[4][3];
#pragma unroll
    for (int u = 0; u < 4; ++u) {
        int tr = dir ? (Lmax - 1 - u) : u;
        int t = min(max(tr, 0), Lmax - 1);
#pragma unroll
        for (int gate = 0; gate < 3; ++gate)
            ring[u][gate] = gbase[(size_t)t * 1536 + loff[gate]];
    }
    lds_barrier();   // zero-init visible

    for (int sb = 0; sb < S4; sb += 4) {
#pragma unroll
        for (int u = 0; u < 4; ++u) {
            int s = sb + u;
            int tr = dir ? (Lmax - 1 - s) : s;
            int t = min(max(tr, 0), Lmax - 1);     // clamped for tail steps
            const bf16_t* hc = hl + (s & 1) * HBUF;
            bf16_t* hn = hl + ((s + 1) & 1) * HBUF;

            // consume ring slot u (loads issued 4 steps ago); prescaled values
            float gx0 = (float)ring[u][0];   // -log2e * gx_r
            float gx1 = (float)ring[u][1];   // -log2e * gx_z
            float gx2 = (float)ring[u][2];   // 2log2e * gx_n

            // A fragments from LDS h (broadcast rows: sample = row >> 2)
            bf16x8 a[4];
#pragma unroll
            for (int kc = 0; kc < 4; ++kc)
                a[kc] = ldb8(hc + aoff + kc * 32);

            // 3 chains; bhn folded into n-gate C-init (R0 order, compiler-scheduled)
            floatx4 cr = {0.f, 0.f, 0.f, 0.f};
            floatx4 cz = {0.f, 0.f, 0.f, 0.f};
            floatx4 cn = {bhn, bhn, bhn, bhn};
#pragma unroll
            for (int kc = 0; kc < 4; ++kc) {
                cr = __builtin_amdgcn_mfma_f32_16x16x32_bf16(a[kc], Bw[0][kc], cr, 0, 0, 0);
                cz = __builtin_amdgcn_mfma_f32_16x16x32_bf16(a[kc], Bw[1][kc], cz, 0, 0, 0);
                cn = __builtin_amdgcn_mfma_f32_16x16x32_bf16(a[kc], Bw[2][kc], cn, 0, 0, 0);
            }

            // refill ring slot u for step s+4
            {
                int sn = s + 4;
                int trn = dir ? (Lmax - 1 - sn) : sn;
                int tn = min(max(trn, 0), Lmax - 1);
#pragma unroll
                for (int gate = 0; gate < 3; ++gate)
                    ring[u][gate] = gbase[(size_t)tn * 1536 + loff[gate]];
            }

            // all 4 D-regs equal (rows quad*4+r all carry sample quad) -> [0]
            float rg = fast_rcp(1.0f + exp2_f(cr[0] + gx0));       // sigmoid
            float zg = fast_rcp(1.0f + exp2_f(cz[0] + gx1));       // sigmoid
            float v  = fmaf(rg, cn[0], gx2);                       // scaled tanh-arg
            float ng = fmaf(-2.0f, fast_rcp(exp2_f(v) + 1.0f), 1.0f);  // tanh
            float hnew = fmaf(zg, h - ng, ng);                     // (1-z)n + z*h

            bool upd = (s < Lmax) && (t < len1);
            h = upd ? hnew : h;
            bf16_t h16 = (bf16_t)h;
            hn[quad * HPAD + j] = h16;            // LDS row = sample
            hb[(size_t)t * 512 + hoff] = h16;     // hist2 per-block region

            lds_barrier();   // new h visible; old buffer free
        }
    }
}

// -------- K45 (fused K4+K5): one block per sample. Per 16-t chunk (only
// t < len): scores via MFMA with M-dim = time (A rows = 16 consecutive t,
// K=256 over h_f||h_b, N=128 output channels), then in-block softmax over
// valid t and pooled = sum_t alpha[t]*Hout[b][t][:]. hist2 rows at t>=len are
// stale/poison but FINITE (0xAA bf16 = -3e-13) and masked by t<len.
// NEW: pooled phase coalesced — thread = (t-stride, 8-channel octet), bf16x8
// loads (16B coalesced) instead of 512 scalar loads at 1KB stride per lane.
__global__ __launch_bounds__(256) void k45_pool(const bf16_t* __restrict__ hist2,
                                                const bf16_t* __restrict__ wh2o_bf,
                                                const float* __restrict__ bh2o,
                                                const float* __restrict__ uw,
                                                const int* __restrict__ lens,
                                                float* __restrict__ out) {
    int b = blockIdx.x;
    int g16 = b >> 2, bl = b & 3;
    int tid = threadIdx.x;
    int lane = tid & 63, w2 = tid >> 6;       // 4 waves
    int quad = lane >> 4, col = lane & 15;
    int len = lens[b];

    __shared__ float smax[TT][4];   // per-wave partial scores, 8 KB (reused as red2)
    __shared__ float alpha[TT];
    __shared__ float red[256];

    const bf16_t* hf = hist2 + (size_t)g16 * TT * 512 + bl * 128;        // fwd
    const bf16_t* hbk = hist2 + (size_t)(16 + g16) * TT * 512 + bl * 128; // bwd

    // this wave's 2 n-tiles (N=128 total over 4 waves)
    int n0 = (w2 * 2 + 0) * 16 + col;
    int n1 = (w2 * 2 + 1) * 16 + col;
    float bias0 = bh2o[n0], u0 = uw[n0];
    float bias1 = bh2o[n1], u1 = uw[n1];

    int nch = (len + 15) >> 4;
    for (int ch = 0; ch < nch; ++ch) {
        int t0 = ch * 16;
        int t = t0 + col;                 // A row m = t offset (t <= 511)
        bf16x8 a[8];
#pragma unroll
        for (int kc = 0; kc < 4; ++kc) {
            a[kc]     = ldb8(hf  + (size_t)t * 512 + kc * 32 + quad * 8);
            a[kc + 4] = ldb8(hbk + (size_t)t * 512 + kc * 32 + quad * 8);
        }
        float p4[4] = {0.f, 0.f, 0.f, 0.f};
#pragma unroll
        for (int tl = 0; tl < 2; ++tl) {
            int n = tl ? n1 : n0;
            float bias = tl ? bias1 : bias0;
            float u = tl ? u1 : u0;
            floatx4 acc = {0.f, 0.f, 0.f, 0.f};
#pragma unroll
            for (int kc = 0; kc < 8; ++kc) {
                bf16x8 bw = ldb8(wh2o_bf + (size_t)n * 256 + kc * 32 + quad * 8);
                acc = __builtin_amdgcn_mfma_f32_16x16x32_bf16(a[kc], bw, acc, 0, 0, 0);
            }
#pragma unroll
            for (int r = 0; r < 4; ++r)
                p4[r] += tanh_f(acc[r] + bias) * u;
        }
        // reduce over the 16 cols of this quad group (D rows = t's)
#pragma unroll
        for (int m = 1; m < 16; m <<= 1)
#pragma unroll
            for (int r = 0; r < 4; ++r)
                p4[r] += __shfl_xor(p4[r], m, 64);
        if (col == 0) {
#pragma unroll
            for (int r = 0; r < 4; ++r)
                smax[t0 + quad * 4 + r][w2] = p4[r];
        }
    }
    __syncthreads();

    // softmax over valid t
    float mx = -1e30f;
    for (int t = tid; t < TT; t += 256) {
        float s = -1e30f;
        if (t < len) s = smax[t][0] + smax[t][1] + smax[t][2] + smax[t][3];
        alpha[t] = s;
        mx = fmaxf(mx, s);
    }
    red[tid] = mx;
    __syncthreads();
    for (int s = 128; s > 0; s >>= 1) {
        if (tid < s) red[tid] = fmaxf(red[tid], red[tid + s]);
        __syncthreads();
    }
    mx = red[0];
    __syncthreads();
    float sum = 0.f;
    for (int t = tid; t < TT; t += 256) {
        float e = (t < len) ? __expf(alpha[t] - mx) : 0.f;
        alpha[t] = e;
        sum += e;
    }
    red[tid] = sum;
    __syncthreads();
    for (int s = 128; s > 0; s >>= 1) {
        if (tid < s) red[tid] += red[tid + s];
        __syncthreads();
    }
    float inv = fast_rcp(red[0]);
    __syncthreads();

    // pooled (coalesced): thread = (ts = tid>>5: t stride 8, o = tid&31 octet).
    // dir = o>>4, channels j8..j8+7. Each iter: one 16B bf16x8 load.
    {
        int ts = tid >> 5, o = tid & 31;
        int dirp = o >> 4;
        int j8 = (o & 15) * 8;
        const bf16_t* hbase = (dirp ? hbk : hf) + j8;
        float acc8[8];
#pragma unroll
        for (int e = 0; e < 8; ++e) acc8[e] = 0.f;
        for (int t = ts; t < len; t += 8) {
            float al = alpha[t];
            bf16x8 hv = ldb8(hbase + (size_t)t * 512);
#pragma unroll
            for (int e = 0; e < 8; ++e) acc8[e] = fmaf(al, (float)hv[e], acc8[e]);
        }
        // reduce the 8 t-strides via LDS (reuse smax: 2048 floats)
        float* red2 = &smax[0][0];
#pragma unroll
        for (int e = 0; e < 8; ++e) red2[(ts * 32 + o) * 8 + e] = acc8[e];
        __syncthreads();
        int c = tid;                       // output channel
        int dir2 = c >> 7, rem = c & 127;
        int oo = dir2 * 16 + (rem >> 3), ee = c & 7;
        float acc = 0.f;
#pragma unroll
        for (int q = 0; q < 8; ++q) acc += red2[(q * 32 + oo) * 8 + ee];
        out[(size_t)b * 256 + c] = acc * inv;
    }
}

extern "C" void kernel_launch(void* const* d_in, const int* in_sizes, int n_in,
                              void* d_out, int out_size, void* d_ws, size_t ws_size,
                              hipStream_t stream) {
    const int* X       = (const int*)d_in[0];
    const int* lens    = (const int*)d_in[1];
    const float* emb   = (const float*)d_in[3];
    const float* We2i  = (const float*)d_in[4];
    const float* be2i  = (const float*)d_in[5];
    const float* Wihf  = (const float*)d_in[6];
    const float* Whhf  = (const float*)d_in[7];
    const float* bihf  = (const float*)d_in[8];
    const float* bhhf  = (const float*)d_in[9];
    const float* Wihb  = (const float*)d_in[10];
    const float* Whhb  = (const float*)d_in[11];
    const float* bihb  = (const float*)d_in[12];
    const float* bhhb  = (const float*)d_in[13];
    const float* Wh2o  = (const float*)d_in[14];
    const float* bh2o  = (const float*)d_in[15];
    const float* uw    = (const float*)d_in[16];

    char* ws = (char*)d_ws;
    size_t off = 0;
    bf16_t* we_bf = (bf16_t*)(ws + off);   off += (size_t)HH * EE * 2;          // 32 KB
    bf16_t* wih_bf = (bf16_t*)(ws + off);  off += (size_t)2 * 384 * HH * 2;     // 192 KB
    bf16_t* whh_bf = (bf16_t*)(ws + off);  off += (size_t)2 * 384 * HH * 2;     // 192 KB
    bf16_t* wh2o_bf = (bf16_t*)(ws + off); off += (size_t)OO * 256 * 2;         // 64 KB
    float* gxbias = (float*)(ws + off);    off += 768 * 4;                      // 3 KB
    off = (off + 255) & ~(size_t)255;
    bf16_t* gx3 = (bf16_t*)(ws + off);     off += (size_t)32 * TT * 384 * 4 * 2; // 50.3 MB
    bf16_t* hist2 = (bf16_t*)(ws + off);   off += (size_t)32 * TT * 4 * 128 * 2; // 16.8 MB

    float* out = (float*)d_out;

    k0_conv<<<dim3(256), dim3(256), 0, stream>>>(We2i, Wihf, Wihb, Whhf, Whhb,
                                                 Wh2o, bihf, bhhf, bihb, bhhb,
                                                 we_bf, wih_bf, whh_bf, wh2o_bf, gxbias);
    k12_gx<<<dim3(TT), dim3(256), 0, stream>>>(X, emb, we_bf, be2i, wih_bf, gxbias, lens, gx3);
    k3_gru<<<dim3(16, 2), dim3(512), 0, stream>>>(gx3, whh_bf, bhhf, bhhb, lens, hist2);
    k45_pool<<<dim3(BB), dim3(256), 0, stream>>>(hist2, wh2o_bf, bh2o, uw, lens, out);
}

// Round 4
// 346.398 us; speedup vs baseline: 1.3794x; 1.1177x over previous
//
#include <hip/hip_runtime.h>
#include <hip/hip_bf16.h>

// Shapes (fixed by the problem)
#define VV 50000
#define EE 128
#define HH 128
#define OO 128
#define BB 64
#define TT 512

typedef __bf16 bf16_t;
typedef __attribute__((ext_vector_type(8))) __bf16 bf16x8;
typedef __attribute__((ext_vector_type(4))) __bf16 bf16x4;
typedef __attribute__((ext_vector_type(4))) float floatx4;

// exp2-prescale constants: sigmoid/tanh computed via v_exp_f32 (=2^x) with
// log2e folded into the r/z/n weight rows in k0 (r,z: -log2e; n: +2*log2e).
#define SC_RZ (-1.4426950408889634f)
#define SC_N  (2.8853900817779268f)

__device__ __forceinline__ bf16x8 ldb8(const bf16_t* p) {
    return *reinterpret_cast<const bf16x8*>(p);
}

// load 8 consecutive fp32, round to bf16 fragment (two float4 loads)
__device__ __forceinline__ bf16x8 ldf8_bf(const float* p) {
    const float4* q = reinterpret_cast<const float4*>(p);
    float4 u = q[0], v = q[1];
    bf16x8 r;
    r[0] = (__bf16)u.x; r[1] = (__bf16)u.y; r[2] = (__bf16)u.z; r[3] = (__bf16)u.w;
    r[4] = (__bf16)v.x; r[5] = (__bf16)v.y; r[6] = (__bf16)v.z; r[7] = (__bf16)v.w;
    return r;
}

__device__ __forceinline__ float fast_rcp(float x) { return __builtin_amdgcn_rcpf(x); }
__device__ __forceinline__ float exp2_f(float x) { return __builtin_amdgcn_exp2f(x); }
__device__ __forceinline__ float tanh_f(float x) {
    float e = __expf(2.0f * x);
    return 1.0f - 2.0f * fast_rcp(e + 1.0f);
}

// LDS-only barrier: wait LDS ops, sync — do NOT drain vmcnt (hist stores and
// gx ring-prefetch loads stay in flight across steps).
__device__ __forceinline__ void lds_barrier() {
    asm volatile("s_waitcnt lgkmcnt(0)\n\ts_barrier" ::: "memory");
}

// -------- K0: preconvert small weights fp32->bf16 + fold gx bias.
// exp2 scaling folded into Wih/Whh rows and biases (see SC_RZ/SC_N).
__global__ __launch_bounds__(256) void k0_conv(
    const float* __restrict__ we,
    const float* __restrict__ wihf, const float* __restrict__ wihb,
    const float* __restrict__ whhf, const float* __restrict__ whhb,
    const float* __restrict__ wh2o,
    const float* __restrict__ bihf, const float* __restrict__ bhhf,
    const float* __restrict__ bihb, const float* __restrict__ bhhb,
    bf16_t* __restrict__ we_bf,
    bf16_t* __restrict__ wih_bf, bf16_t* __restrict__ whh_bf,
    bf16_t* __restrict__ wh2o_bf, float* __restrict__ gxbias) {
    int tid = blockIdx.x * 256 + threadIdx.x;
    int np = gridDim.x * 256;
    for (int i = tid; i < HH * EE; i += np) we_bf[i] = (bf16_t)we[i];
    for (int i = tid; i < 384 * HH; i += np) {
        int nrow = i >> 7;                      // row over 384 (HH=128 cols)
        float sc = (nrow < 256) ? SC_RZ : SC_N;
        wih_bf[i] = (bf16_t)(sc * wihf[i]);
        wih_bf[384 * HH + i] = (bf16_t)(sc * wihb[i]);
        whh_bf[i] = (bf16_t)(sc * whhf[i]);
        whh_bf[384 * HH + i] = (bf16_t)(sc * whhb[i]);
    }
    for (int i = tid; i < OO * 256; i += np) wh2o_bf[i] = (bf16_t)wh2o[i];
    if (tid < 768) {
        int dir = tid / 384, n = tid % 384;
        const float* bih = dir ? bihb : bihf;
        const float* bhh = dir ? bhhb : bhhf;
        float sc = (n < 256) ? SC_RZ : SC_N;
        gxbias[tid] = sc * bih[n] + (n < 256 ? sc * bhh[n] : 0.0f);  // bhh_n goes in K3's C-init
    }
}

// -------- K12 (fused K1+K2), 4 timesteps per block, with dead-time skip:
// lens sorted descending -> tile g's max len = lens[16g]; blocks entirely past
// it produce gx no one reads (K3 stops at its group Lmax <= lens[16g]).
__global__ __launch_bounds__(256) void k12_gx(const int* __restrict__ X,
                                              const float* __restrict__ emb,
                                              const bf16_t* __restrict__ we_bf,
                                              const float* __restrict__ be,
                                              const bf16_t* __restrict__ wih_bf,
                                              const float* __restrict__ gxbias,
                                              const int* __restrict__ lens,
                                              bf16_t* __restrict__ gx3) {
    int blk = blockIdx.x;            // 0..511 = tq*4 + g
    int tq = blk >> 2;
    int g = blk & 3;                 // 16-sample tile
    if (4 * tq >= lens[16 * g]) return;   // uniform: whole block dead

    int lane = threadIdx.x & 63;
    int w2 = threadIdx.x >> 6;       // wave 0..3
    int quad = lane >> 4, col = lane & 15;

    __shared__ bf16_t xs[4][16 * 136];   // 4 xh tiles, row-padded

    // stage 1 x4: xh = emb[X] @ We^T + be (A rows = 16 samples at t=4tq+tt)
#pragma unroll
    for (int tt = 0; tt < 4; ++tt) {
        int t = 4 * tq + tt;
        int v = X[(g * 16 + col) * TT + t];
        bf16x8 a[4];
#pragma unroll
        for (int kc = 0; kc < 4; ++kc)
            a[kc] = ldf8_bf(emb + (size_t)v * EE + kc * 32 + quad * 8);
#pragma unroll
        for (int tl = 0; tl < 2; ++tl) {
            int n = 32 * w2 + 16 * tl + col;
            floatx4 acc = {0.f, 0.f, 0.f, 0.f};
#pragma unroll
            for (int kc = 0; kc < 4; ++kc) {
                bf16x8 bw = ldb8(we_bf + (size_t)n * EE + kc * 32 + quad * 8);
                acc = __builtin_amdgcn_mfma_f32_16x16x32_bf16(a[kc], bw, acc, 0, 0, 0);
            }
            float bias = be[n];
#pragma unroll
            for (int r = 0; r < 4; ++r)
                xs[tt][(quad * 4 + r) * 136 + n] = (bf16_t)(acc[r] + bias);
        }
    }
    __syncthreads();

    // stage 2: gx = xh @ Wih^T + gxbias, both dirs; Wih loaded once per n-tile
    bf16x8 a2[4][4];
#pragma unroll
    for (int tt = 0; tt < 4; ++tt)
#pragma unroll
        for (int kc = 0; kc < 4; ++kc)
            a2[tt][kc] = ldb8(xs[tt] + col * 136 + kc * 32 + quad * 8);

#pragma unroll 2
    for (int tl = 0; tl < 12; ++tl) {
        int idx = w2 * 12 + tl;          // 0..47
        int dir = idx >= 24;
        int n = (idx - dir * 24) * 16 + col;   // 0..383
        bf16x8 bw[4];
#pragma unroll
        for (int kc = 0; kc < 4; ++kc)
            bw[kc] = ldb8(wih_bf + ((size_t)dir * 384 + n) * HH + kc * 32 + quad * 8);
        float bias = gxbias[dir * 384 + n];
#pragma unroll
        for (int tt = 0; tt < 4; ++tt) {
            int t = 4 * tq + tt;
            floatx4 acc = {0.f, 0.f, 0.f, 0.f};
#pragma unroll
            for (int kc = 0; kc < 4; ++kc)
                acc = __builtin_amdgcn_mfma_f32_16x16x32_bf16(a2[tt][kc], bw[kc], acc, 0, 0, 0);
            bf16x4 pack;
#pragma unroll
            for (int r = 0; r < 4; ++r)
                pack[r] = (__bf16)(acc[r] + bias);   // D row r -> sample 16g+quad*4+r
            *reinterpret_cast<bf16x4*>(
                gx3 + (((size_t)(dir * 16 + 4 * g + quad) * TT + t) * 384 + n) * 4) = pack;
        }
    }
}

// -------- K3: masked GRU recurrence — R3 structure (194 us measured) with
// per-step VALU trimmed: all t-dependent addressing replaced by saturating
// pointers advanced with scalar-selected increments (no per-step min/max/mul),
// and the update mask via precomputed per-lane [ulo,uhi) bounds on s.
// Read->MFMA->tail spine untouched (R1/R2 showed restructuring regresses).
#define HPAD 144
#define HBUF (4 * HPAD)
__global__ __launch_bounds__(512) void k3_gru(const bf16_t* __restrict__ gx3,
                                              const bf16_t* __restrict__ whh_bf,
                                              const float* __restrict__ bhh_f,
                                              const float* __restrict__ bhh_b,
                                              const int* __restrict__ lens,
                                              bf16_t* __restrict__ hist2) {
    int g16 = blockIdx.x;    // 4-sample group: samples 4*g16 .. 4*g16+3
    int dir = blockIdx.y;
    const float* bhh = dir ? bhh_b : bhh_f;

    int tid = threadIdx.x;
    int w = tid >> 6;        // wave 0..7
    int lane = tid & 63;
    int quad = lane >> 4, col = lane & 15;
    int j = 16 * w + col;    // owned hidden column

    __shared__ bf16_t hl[2 * HBUF];   // double-buffered h, 4 rows (samples)
    for (int i = tid; i < 2 * HBUF; i += 512) hl[i] = (bf16_t)0.f;

    int len1 = lens[4 * g16 + quad];      // this lane's sample
    int Lmax = max(max(lens[4 * g16], lens[4 * g16 + 1]),
                   max(lens[4 * g16 + 2], lens[4 * g16 + 3]));

    float bhn = SC_N * bhh[256 + j];      // n-row scale applied (C-init)

    // Whh B-fragments (pre-converted bf16, pre-scaled), resident for all steps
    bf16x8 Bw[3][4];
#pragma unroll
    for (int gate = 0; gate < 3; ++gate)
#pragma unroll
        for (int kc = 0; kc < 4; ++kc)
            Bw[gate][kc] = ldb8(whh_bf + ((size_t)dir * 384 + gate * 128 + j) * HH + kc * 32 + quad * 8);

    const bf16_t* gbase = gx3 + (size_t)(dir * 16 + g16) * TT * 1536;
    bf16_t* hb = hist2 + (size_t)(dir * 16 + g16) * TT * 512;
    int loff[3];
#pragma unroll
    for (int gate = 0; gate < 3; ++gate)
        loff[gate] = (gate * 128 + j) * 4 + quad;
    int hoff = quad * 128 + j;
    int aoff = (col >> 2) * HPAD + quad * 8;   // broadcast A-read: row m -> sample m>>2

    float h = 0.f;
    int S4 = (Lmax + 3) & ~3;

    // prefetch ring, depth 4 (raw bf16 scalars; convert at consumption).
    // Lmax >= 64 always (lens in [64,512]) -> initial fills need no clamps.
    __bf16 ring[4][3];
#pragma unroll
    for (int u = 0; u < 4; ++u) {
        int t = dir ? (Lmax - 1 - u) : u;
#pragma unroll
        for (int gate = 0; gate < 3; ++gate)
            ring[u][gate] = gbase[(size_t)t * 1536 + loff[gate]];
    }
    lds_barrier();   // zero-init visible

    // saturating stream pointers (replace per-step clamp+mul addressing)
    int gstep = dir ? -1536 : 1536;       // gx3 elements per t
    int hstep = dir ? -512 : 512;         // hist2 elements per t
    const bf16_t* rp0 = gbase + (size_t)(dir ? (Lmax - 5) : 4) * 1536 + loff[0];
    const bf16_t* rp1 = gbase + (size_t)(dir ? (Lmax - 5) : 4) * 1536 + loff[1];
    const bf16_t* rp2 = gbase + (size_t)(dir ? (Lmax - 5) : 4) * 1536 + loff[2];
    bf16_t* hp = hb + (size_t)(dir ? (Lmax - 1) : 0) * 512 + hoff;
    int ulo = dir ? (Lmax - len1) : 0;    // upd  <=>  ulo <= s < uhi
    int uhi = dir ? Lmax : len1;

    for (int sb = 0; sb < S4; sb += 4) {
#pragma unroll
        for (int u = 0; u < 4; ++u) {
            int s = sb + u;
            const bf16_t* hc = hl + (s & 1) * HBUF;
            bf16_t* hn = hl + ((s + 1) & 1) * HBUF;

            // consume ring slot u (loads issued 4 steps ago); prescaled values
            float gx0 = (float)ring[u][0];   // -log2e * gx_r
            float gx1 = (float)ring[u][1];   // -log2e * gx_z
            float gx2 = (float)ring[u][2];   // 2log2e * gx_n

            // A fragments from LDS h (broadcast rows: sample = row >> 2)
            bf16x8 a[4];
#pragma unroll
            for (int kc = 0; kc < 4; ++kc)
                a[kc] = ldb8(hc + aoff + kc * 32);

            // 3 chains; bhn folded into n-gate C-init (compiler-scheduled)
            floatx4 cr = {0.f, 0.f, 0.f, 0.f};
            floatx4 cz = {0.f, 0.f, 0.f, 0.f};
            floatx4 cn = {bhn, bhn, bhn, bhn};
#pragma unroll
            for (int kc = 0; kc < 4; ++kc) {
                cr = __builtin_amdgcn_mfma_f32_16x16x32_bf16(a[kc], Bw[0][kc], cr, 0, 0, 0);
                cz = __builtin_amdgcn_mfma_f32_16x16x32_bf16(a[kc], Bw[1][kc], cz, 0, 0, 0);
                cn = __builtin_amdgcn_mfma_f32_16x16x32_bf16(a[kc], Bw[2][kc], cn, 0, 0, 0);
            }

            // refill ring slot u for step s+4 (pointers saturate at the ends)
            ring[u][0] = *rp0;
            ring[u][1] = *rp1;
            ring[u][2] = *rp2;
            {
                int adv = (s < Lmax - 5) ? gstep : 0;   // scalar select
                rp0 += adv; rp1 += adv; rp2 += adv;
            }

            // all 4 D-regs equal (rows quad*4+r all carry sample quad) -> [0]
            float rg = fast_rcp(1.0f + exp2_f(cr[0] + gx0));       // sigmoid
            float zg = fast_rcp(1.0f + exp2_f(cz[0] + gx1));       // sigmoid
            float v  = fmaf(rg, cn[0], gx2);                       // scaled tanh-arg
            float ng = fmaf(-2.0f, fast_rcp(exp2_f(v) + 1.0f), 1.0f);  // tanh
            float hnew = fmaf(zg, h - ng, ng);                     // (1-z)n + z*h

            bool upd = (s >= ulo) && (s < uhi);
            h = upd ? hnew : h;
            bf16_t h16 = (bf16_t)h;
            hn[quad * HPAD + j] = h16;            // LDS row = sample
            *hp = h16;                            // hist2 per-block region
            hp += (s < Lmax - 1) ? hstep : 0;

            lds_barrier();   // new h visible; old buffer free
        }
    }
}

// -------- K45 (fused K4+K5): one block per sample. Per 16-t chunk (only
// t < len): scores via MFMA with M-dim = time, then in-block softmax over
// valid t and pooled = sum_t alpha[t]*Hout[b][t][:]. hist2 rows at t>=len are
// stale/poison but FINITE and masked by t<len.
// NEW: wh2o B-fragments hoisted out of the chunk loop (loaded once, resident
// in VGPRs) and hist2 A-loads software-pipelined one chunk ahead — removes an
// L2-latency chain from every chunk.
__global__ __launch_bounds__(256) void k45_pool(const bf16_t* __restrict__ hist2,
                                                const bf16_t* __restrict__ wh2o_bf,
                                                const float* __restrict__ bh2o,
                                                const float* __restrict__ uw,
                                                const int* __restrict__ lens,
                                                float* __restrict__ out) {
    int b = blockIdx.x;
    int g16 = b >> 2, bl = b & 3;
    int tid = threadIdx.x;
    int lane = tid & 63, w2 = tid >> 6;       // 4 waves
    int quad = lane >> 4, col = lane & 15;
    int len = lens[b];

    __shared__ float smax[TT][4];   // per-wave partial scores, 8 KB (reused as red2)
    __shared__ float alpha[TT];
    __shared__ float red[256];

    const bf16_t* hf = hist2 + (size_t)g16 * TT * 512 + bl * 128;        // fwd
    const bf16_t* hbk = hist2 + (size_t)(16 + g16) * TT * 512 + bl * 128; // bwd

    // this wave's 2 n-tiles (N=128 total over 4 waves)
    int n0 = (w2 * 2 + 0) * 16 + col;
    int n1 = (w2 * 2 + 1) * 16 + col;
    float bias0 = bh2o[n0], u0 = uw[n0];
    float bias1 = bh2o[n1], u1 = uw[n1];

    // resident B-fragments (2 n-tiles x 8 kc x 16B = 64 VGPR)
    bf16x8 bw0[8], bw1[8];
#pragma unroll
    for (int kc = 0; kc < 8; ++kc) {
        bw0[kc] = ldb8(wh2o_bf + (size_t)n0 * 256 + kc * 32 + quad * 8);
        bw1[kc] = ldb8(wh2o_bf + (size_t)n1 * 256 + kc * 32 + quad * 8);
    }

    int nch = (len + 15) >> 4;
    bf16x8 a[8], an[8];
    {   // prime chunk 0 (t = col, always in-bounds: t <= 511)
        int t = col;
#pragma unroll
        for (int kc = 0; kc < 4; ++kc) {
            a[kc]     = ldb8(hf  + (size_t)t * 512 + kc * 32 + quad * 8);
            a[kc + 4] = ldb8(hbk + (size_t)t * 512 + kc * 32 + quad * 8);
        }
    }
    for (int ch = 0; ch < nch; ++ch) {
        int t0 = ch * 16;
        // prefetch next chunk's A (clamped; all t <= 511 so loads stay valid)
        {
            int tn = (ch + 1 < nch ? t0 + 16 : t0) + col;
#pragma unroll
            for (int kc = 0; kc < 4; ++kc) {
                an[kc]     = ldb8(hf  + (size_t)tn * 512 + kc * 32 + quad * 8);
                an[kc + 4] = ldb8(hbk + (size_t)tn * 512 + kc * 32 + quad * 8);
            }
        }
        float p4[4] = {0.f, 0.f, 0.f, 0.f};
#pragma unroll
        for (int tl = 0; tl < 2; ++tl) {
            float bias = tl ? bias1 : bias0;
            float u = tl ? u1 : u0;
            floatx4 acc = {0.f, 0.f, 0.f, 0.f};
#pragma unroll
            for (int kc = 0; kc < 8; ++kc) {
                bf16x8 bw = tl ? bw1[kc] : bw0[kc];
                acc = __builtin_amdgcn_mfma_f32_16x16x32_bf16(a[kc], bw, acc, 0, 0, 0);
            }
#pragma unroll
            for (int r = 0; r < 4; ++r)
                p4[r] += tanh_f(acc[r] + bias) * u;
        }
        // reduce over the 16 cols of this quad group (D rows = t's)
#pragma unroll
        for (int m = 1; m < 16; m <<= 1)
#pragma unroll
            for (int r = 0; r < 4; ++r)
                p4[r] += __shfl_xor(p4[r], m, 64);
        if (col == 0) {
#pragma unroll
            for (int r = 0; r < 4; ++r)
                smax[t0 + quad * 4 + r][w2] = p4[r];
        }
#pragma unroll
        for (int kc = 0; kc < 8; ++kc) a[kc] = an[kc];
    }
    __syncthreads();

    // softmax over valid t
    float mx = -1e30f;
    for (int t = tid; t < TT; t += 256) {
        float s = -1e30f;
        if (t < len) s = smax[t][0] + smax[t][1] + smax[t][2] + smax[t][3];
        alpha[t] = s;
        mx = fmaxf(mx, s);
    }
    red[tid] = mx;
    __syncthreads();
    for (int s = 128; s > 0; s >>= 1) {
        if (tid < s) red[tid] = fmaxf(red[tid], red[tid + s]);
        __syncthreads();
    }
    mx = red[0];
    __syncthreads();
    float sum = 0.f;
    for (int t = tid; t < TT; t += 256) {
        float e = (t < len) ? __expf(alpha[t] - mx) : 0.f;
        alpha[t] = e;
        sum += e;
    }
    red[tid] = sum;
    __syncthreads();
    for (int s = 128; s > 0; s >>= 1) {
        if (tid < s) red[tid] += red[tid + s];
        __syncthreads();
    }
    float inv = fast_rcp(red[0]);
    __syncthreads();

    // pooled (coalesced): thread = (ts = tid>>5: t stride 8, o = tid&31 octet).
    // dir = o>>4, channels j8..j8+7. Each iter: one 16B bf16x8 load.
    {
        int ts = tid >> 5, o = tid & 31;
        int dirp = o >> 4;
        int j8 = (o & 15) * 8;
        const bf16_t* hbase = (dirp ? hbk : hf) + j8;
        float acc8[8];
#pragma unroll
        for (int e = 0; e < 8; ++e) acc8[e] = 0.f;
        for (int t = ts; t < len; t += 8) {
            float al = alpha[t];
            bf16x8 hv = ldb8(hbase + (size_t)t * 512);
#pragma unroll
            for (int e = 0; e < 8; ++e) acc8[e] = fmaf(al, (float)hv[e], acc8[e]);
        }
        // reduce the 8 t-strides via LDS (reuse smax: 2048 floats)
        float* red2 = &smax[0][0];
#pragma unroll
        for (int e = 0; e < 8; ++e) red2[(ts * 32 + o) * 8 + e] = acc8[e];
        __syncthreads();
        int c = tid;                       // output channel
        int dir2 = c >> 7, rem = c & 127;
        int oo = dir2 * 16 + (rem >> 3), ee = c & 7;
        float acc = 0.f;
#pragma unroll
        for (int q = 0; q < 8; ++q) acc += red2[(q * 32 + oo) * 8 + ee];
        out[(size_t)b * 256 + c] = acc * inv;
    }
}

extern "C" void kernel_launch(void* const* d_in, const int* in_sizes, int n_in,
                              void* d_out, int out_size, void* d_ws, size_t ws_size,
                              hipStream_t stream) {
    const int* X       = (const int*)d_in[0];
    const int* lens    = (const int*)d_in[1];
    const float* emb   = (const float*)d_in[3];
    const float* We2i  = (const float*)d_in[4];
    const float* be2i  = (const float*)d_in[5];
    const float* Wihf  = (const float*)d_in[6];
    const float* Whhf  = (const float*)d_in[7];
    const float* bihf  = (const float*)d_in[8];
    const float* bhhf  = (const float*)d_in[9];
    const float* Wihb  = (const float*)d_in[10];
    const float* Whhb  = (const float*)d_in[11];
    const float* bihb  = (const float*)d_in[12];
    const float* bhhb  = (const float*)d_in[13];
    const float* Wh2o  = (const float*)d_in[14];
    const float* bh2o  = (const float*)d_in[15];
    const float* uw    = (const float*)d_in[16];

    char* ws = (char*)d_ws;
    size_t off = 0;
    bf16_t* we_bf = (bf16_t*)(ws + off);   off += (size_t)HH * EE * 2;          // 32 KB
    bf16_t* wih_bf = (bf16_t*)(ws + off);  off += (size_t)2 * 384 * HH * 2;     // 192 KB
    bf16_t* whh_bf = (bf16_t*)(ws + off);  off += (size_t)2 * 384 * HH * 2;     // 192 KB
    bf16_t* wh2o_bf = (bf16_t*)(ws + off); off += (size_t)OO * 256 * 2;         // 64 KB
    float* gxbias = (float*)(ws + off);    off += 768 * 4;                      // 3 KB
    off = (off + 255) & ~(size_t)255;
    bf16_t* gx3 = (bf16_t*)(ws + off);     off += (size_t)32 * TT * 384 * 4 * 2; // 50.3 MB
    bf16_t* hist2 = (bf16_t*)(ws + off);   off += (size_t)32 * TT * 4 * 128 * 2; // 16.8 MB

    float* out = (float*)d_out;

    k0_conv<<<dim3(256), dim3(256), 0, stream>>>(We2i, Wihf, Wihb, Whhf, Whhb,
                                                 Wh2o, bihf, bhhf, bihb, bhhb,
                                                 we_bf, wih_bf, whh_bf, wh2o_bf, gxbias);
    k12_gx<<<dim3(TT), dim3(256), 0, stream>>>(X, emb, we_bf, be2i, wih_bf, gxbias, lens, gx3);
    k3_gru<<<dim3(16, 2), dim3(512), 0, stream>>>(gx3, whh_bf, bhhf, bhhb, lens, hist2);
    k45_pool<<<dim3(BB), dim3(256), 0, stream>>>(hist2, wh2o_bf, bh2o, uw, lens, out);
}

// Round 5
// 342.112 us; speedup vs baseline: 1.3966x; 1.0125x over previous
//
#include <hip/hip_runtime.h>
#include <hip/hip_bf16.h>

// Shapes (fixed by the problem)
#define VV 50000
#define EE 128
#define HH 128
#define OO 128
#define BB 64
#define TT 512

typedef __bf16 bf16_t;
typedef __attribute__((ext_vector_type(8))) __bf16 bf16x8;
typedef __attribute__((ext_vector_type(4))) __bf16 bf16x4;
typedef __attribute__((ext_vector_type(4))) float floatx4;

// exp2-prescale constants: sigmoid/tanh computed via v_exp_f32 (=2^x) with
// log2e folded into the r/z/n weight rows in k0 (r,z: -log2e; n: +2*log2e).
#define SC_RZ (-1.4426950408889634f)
#define SC_N  (2.8853900817779268f)

__device__ __forceinline__ bf16x8 ldb8(const bf16_t* p) {
    return *reinterpret_cast<const bf16x8*>(p);
}

// load 8 consecutive fp32, round to bf16 fragment (two float4 loads)
__device__ __forceinline__ bf16x8 ldf8_bf(const float* p) {
    const float4* q = reinterpret_cast<const float4*>(p);
    float4 u = q[0], v = q[1];
    bf16x8 r;
    r[0] = (__bf16)u.x; r[1] = (__bf16)u.y; r[2] = (__bf16)u.z; r[3] = (__bf16)u.w;
    r[4] = (__bf16)v.x; r[5] = (__bf16)v.y; r[6] = (__bf16)v.z; r[7] = (__bf16)v.w;
    return r;
}

__device__ __forceinline__ float fast_rcp(float x) { return __builtin_amdgcn_rcpf(x); }
__device__ __forceinline__ float exp2_f(float x) { return __builtin_amdgcn_exp2f(x); }
__device__ __forceinline__ float tanh_f(float x) {
    float e = __expf(2.0f * x);
    return 1.0f - 2.0f * fast_rcp(e + 1.0f);
}

// LDS-only barrier: wait LDS ops, sync — do NOT drain vmcnt (hist stores and
// gx ring-prefetch loads stay in flight across steps).
__device__ __forceinline__ void lds_barrier() {
    asm volatile("s_waitcnt lgkmcnt(0)\n\ts_barrier" ::: "memory");
}

// -------- K0: preconvert small weights fp32->bf16 + fold gx bias.
// exp2 scaling folded into Wih/Whh rows and biases (see SC_RZ/SC_N).
__global__ __launch_bounds__(256) void k0_conv(
    const float* __restrict__ we,
    const float* __restrict__ wihf, const float* __restrict__ wihb,
    const float* __restrict__ whhf, const float* __restrict__ whhb,
    const float* __restrict__ wh2o,
    const float* __restrict__ bihf, const float* __restrict__ bhhf,
    const float* __restrict__ bihb, const float* __restrict__ bhhb,
    bf16_t* __restrict__ we_bf,
    bf16_t* __restrict__ wih_bf, bf16_t* __restrict__ whh_bf,
    bf16_t* __restrict__ wh2o_bf, float* __restrict__ gxbias) {
    int tid = blockIdx.x * 256 + threadIdx.x;
    int np = gridDim.x * 256;
    for (int i = tid; i < HH * EE; i += np) we_bf[i] = (bf16_t)we[i];
    for (int i = tid; i < 384 * HH; i += np) {
        int nrow = i >> 7;                      // row over 384 (HH=128 cols)
        float sc = (nrow < 256) ? SC_RZ : SC_N;
        wih_bf[i] = (bf16_t)(sc * wihf[i]);
        wih_bf[384 * HH + i] = (bf16_t)(sc * wihb[i]);
        whh_bf[i] = (bf16_t)(sc * whhf[i]);
        whh_bf[384 * HH + i] = (bf16_t)(sc * whhb[i]);
    }
    for (int i = tid; i < OO * 256; i += np) wh2o_bf[i] = (bf16_t)wh2o[i];
    if (tid < 768) {
        int dir = tid / 384, n = tid % 384;
        const float* bih = dir ? bihb : bihf;
        const float* bhh = dir ? bhhb : bhhf;
        float sc = (n < 256) ? SC_RZ : SC_N;
        gxbias[tid] = sc * bih[n] + (n < 256 ? sc * bhh[n] : 0.0f);  // bhh_n goes in K3's C-init
    }
}

// -------- K12 (fused K1+K2), 4 timesteps per block, with dead-time skip:
// lens sorted descending -> tile g's max len = lens[16g]; blocks entirely past
// it produce gx no one reads (K3 stops at its group Lmax <= lens[16g]).
__global__ __launch_bounds__(256) void k12_gx(const int* __restrict__ X,
                                              const float* __restrict__ emb,
                                              const bf16_t* __restrict__ we_bf,
                                              const float* __restrict__ be,
                                              const bf16_t* __restrict__ wih_bf,
                                              const float* __restrict__ gxbias,
                                              const int* __restrict__ lens,
                                              bf16_t* __restrict__ gx3) {
    int blk = blockIdx.x;            // 0..511 = tq*4 + g
    int tq = blk >> 2;
    int g = blk & 3;                 // 16-sample tile
    if (4 * tq >= lens[16 * g]) return;   // uniform: whole block dead

    int lane = threadIdx.x & 63;
    int w2 = threadIdx.x >> 6;       // wave 0..3
    int quad = lane >> 4, col = lane & 15;

    __shared__ bf16_t xs[4][16 * 136];   // 4 xh tiles, row-padded

    // stage 1 x4: xh = emb[X] @ We^T + be (A rows = 16 samples at t=4tq+tt)
#pragma unroll
    for (int tt = 0; tt < 4; ++tt) {
        int t = 4 * tq + tt;
        int v = X[(g * 16 + col) * TT + t];
        bf16x8 a[4];
#pragma unroll
        for (int kc = 0; kc < 4; ++kc)
            a[kc] = ldf8_bf(emb + (size_t)v * EE + kc * 32 + quad * 8);
#pragma unroll
        for (int tl = 0; tl < 2; ++tl) {
            int n = 32 * w2 + 16 * tl + col;
            floatx4 acc = {0.f, 0.f, 0.f, 0.f};
#pragma unroll
            for (int kc = 0; kc < 4; ++kc) {
                bf16x8 bw = ldb8(we_bf + (size_t)n * EE + kc * 32 + quad * 8);
                acc = __builtin_amdgcn_mfma_f32_16x16x32_bf16(a[kc], bw, acc, 0, 0, 0);
            }
            float bias = be[n];
#pragma unroll
            for (int r = 0; r < 4; ++r)
                xs[tt][(quad * 4 + r) * 136 + n] = (bf16_t)(acc[r] + bias);
        }
    }
    __syncthreads();

    // stage 2: gx = xh @ Wih^T + gxbias, both dirs; Wih loaded once per n-tile
    bf16x8 a2[4][4];
#pragma unroll
    for (int tt = 0; tt < 4; ++tt)
#pragma unroll
        for (int kc = 0; kc < 4; ++kc)
            a2[tt][kc] = ldb8(xs[tt] + col * 136 + kc * 32 + quad * 8);

#pragma unroll 2
    for (int tl = 0; tl < 12; ++tl) {
        int idx = w2 * 12 + tl;          // 0..47
        int dir = idx >= 24;
        int n = (idx - dir * 24) * 16 + col;   // 0..383
        bf16x8 bw[4];
#pragma unroll
        for (int kc = 0; kc < 4; ++kc)
            bw[kc] = ldb8(wih_bf + ((size_t)dir * 384 + n) * HH + kc * 32 + quad * 8);
        float bias = gxbias[dir * 384 + n];
#pragma unroll
        for (int tt = 0; tt < 4; ++tt) {
            int t = 4 * tq + tt;
            floatx4 acc = {0.f, 0.f, 0.f, 0.f};
#pragma unroll
            for (int kc = 0; kc < 4; ++kc)
                acc = __builtin_amdgcn_mfma_f32_16x16x32_bf16(a2[tt][kc], bw[kc], acc, 0, 0, 0);
            bf16x4 pack;
#pragma unroll
            for (int r = 0; r < 4; ++r)
                pack[r] = (__bf16)(acc[r] + bias);   // D row r -> sample 16g+quad*4+r
            *reinterpret_cast<bf16x4*>(
                gx3 + (((size_t)(dir * 16 + 4 * g + quad) * TT + t) * 384 + n) * 4) = pack;
        }
    }
}

// -------- K3: masked GRU recurrence — FROZEN at R4 (179 us measured).
// 8 waves, saturating stream pointers, exp2-prescaled weights, broadcast
// A-layout row=col>>2 (no selects). R1/R2 showed restructuring regresses.
#define HPAD 144
#define HBUF (4 * HPAD)
__global__ __launch_bounds__(512) void k3_gru(const bf16_t* __restrict__ gx3,
                                              const bf16_t* __restrict__ whh_bf,
                                              const float* __restrict__ bhh_f,
                                              const float* __restrict__ bhh_b,
                                              const int* __restrict__ lens,
                                              bf16_t* __restrict__ hist2) {
    int g16 = blockIdx.x;    // 4-sample group: samples 4*g16 .. 4*g16+3
    int dir = blockIdx.y;
    const float* bhh = dir ? bhh_b : bhh_f;

    int tid = threadIdx.x;
    int w = tid >> 6;        // wave 0..7
    int lane = tid & 63;
    int quad = lane >> 4, col = lane & 15;
    int j = 16 * w + col;    // owned hidden column

    __shared__ bf16_t hl[2 * HBUF];   // double-buffered h, 4 rows (samples)
    for (int i = tid; i < 2 * HBUF; i += 512) hl[i] = (bf16_t)0.f;

    int len1 = lens[4 * g16 + quad];      // this lane's sample
    int Lmax = max(max(lens[4 * g16], lens[4 * g16 + 1]),
                   max(lens[4 * g16 + 2], lens[4 * g16 + 3]));

    float bhn = SC_N * bhh[256 + j];      // n-row scale applied (C-init)

    // Whh B-fragments (pre-converted bf16, pre-scaled), resident for all steps
    bf16x8 Bw[3][4];
#pragma unroll
    for (int gate = 0; gate < 3; ++gate)
#pragma unroll
        for (int kc = 0; kc < 4; ++kc)
            Bw[gate][kc] = ldb8(whh_bf + ((size_t)dir * 384 + gate * 128 + j) * HH + kc * 32 + quad * 8);

    const bf16_t* gbase = gx3 + (size_t)(dir * 16 + g16) * TT * 1536;
    bf16_t* hb = hist2 + (size_t)(dir * 16 + g16) * TT * 512;
    int loff[3];
#pragma unroll
    for (int gate = 0; gate < 3; ++gate)
        loff[gate] = (gate * 128 + j) * 4 + quad;
    int hoff = quad * 128 + j;
    int aoff = (col >> 2) * HPAD + quad * 8;   // broadcast A-read: row m -> sample m>>2

    float h = 0.f;
    int S4 = (Lmax + 3) & ~3;

    // prefetch ring, depth 4 (raw bf16 scalars; convert at consumption).
    // Lmax >= 64 always (lens in [64,512]) -> initial fills need no clamps.
    __bf16 ring[4][3];
#pragma unroll
    for (int u = 0; u < 4; ++u) {
        int t = dir ? (Lmax - 1 - u) : u;
#pragma unroll
        for (int gate = 0; gate < 3; ++gate)
            ring[u][gate] = gbase[(size_t)t * 1536 + loff[gate]];
    }
    lds_barrier();   // zero-init visible

    // saturating stream pointers (replace per-step clamp+mul addressing)
    int gstep = dir ? -1536 : 1536;       // gx3 elements per t
    int hstep = dir ? -512 : 512;         // hist2 elements per t
    const bf16_t* rp0 = gbase + (size_t)(dir ? (Lmax - 5) : 4) * 1536 + loff[0];
    const bf16_t* rp1 = gbase + (size_t)(dir ? (Lmax - 5) : 4) * 1536 + loff[1];
    const bf16_t* rp2 = gbase + (size_t)(dir ? (Lmax - 5) : 4) * 1536 + loff[2];
    bf16_t* hp = hb + (size_t)(dir ? (Lmax - 1) : 0) * 512 + hoff;
    int ulo = dir ? (Lmax - len1) : 0;    // upd  <=>  ulo <= s < uhi
    int uhi = dir ? Lmax : len1;

    for (int sb = 0; sb < S4; sb += 4) {
#pragma unroll
        for (int u = 0; u < 4; ++u) {
            int s = sb + u;
            const bf16_t* hc = hl + (s & 1) * HBUF;
            bf16_t* hn = hl + ((s + 1) & 1) * HBUF;

            // consume ring slot u (loads issued 4 steps ago); prescaled values
            float gx0 = (float)ring[u][0];   // -log2e * gx_r
            float gx1 = (float)ring[u][1];   // -log2e * gx_z
            float gx2 = (float)ring[u][2];   // 2log2e * gx_n

            // A fragments from LDS h (broadcast rows: sample = row >> 2)
            bf16x8 a[4];
#pragma unroll
            for (int kc = 0; kc < 4; ++kc)
                a[kc] = ldb8(hc + aoff + kc * 32);

            // 3 chains; bhn folded into n-gate C-init (compiler-scheduled)
            floatx4 cr = {0.f, 0.f, 0.f, 0.f};
            floatx4 cz = {0.f, 0.f, 0.f, 0.f};
            floatx4 cn = {bhn, bhn, bhn, bhn};
#pragma unroll
            for (int kc = 0; kc < 4; ++kc) {
                cr = __builtin_amdgcn_mfma_f32_16x16x32_bf16(a[kc], Bw[0][kc], cr, 0, 0, 0);
                cz = __builtin_amdgcn_mfma_f32_16x16x32_bf16(a[kc], Bw[1][kc], cz, 0, 0, 0);
                cn = __builtin_amdgcn_mfma_f32_16x16x32_bf16(a[kc], Bw[2][kc], cn, 0, 0, 0);
            }

            // refill ring slot u for step s+4 (pointers saturate at the ends)
            ring[u][0] = *rp0;
            ring[u][1] = *rp1;
            ring[u][2] = *rp2;
            {
                int adv = (s < Lmax - 5) ? gstep : 0;   // scalar select
                rp0 += adv; rp1 += adv; rp2 += adv;
            }

            // all 4 D-regs equal (rows quad*4+r all carry sample quad) -> [0]
            float rg = fast_rcp(1.0f + exp2_f(cr[0] + gx0));       // sigmoid
            float zg = fast_rcp(1.0f + exp2_f(cz[0] + gx1));       // sigmoid
            float v  = fmaf(rg, cn[0], gx2);                       // scaled tanh-arg
            float ng = fmaf(-2.0f, fast_rcp(exp2_f(v) + 1.0f), 1.0f);  // tanh
            float hnew = fmaf(zg, h - ng, ng);                     // (1-z)n + z*h

            bool upd = (s >= ulo) && (s < uhi);
            h = upd ? hnew : h;
            bf16_t h16 = (bf16_t)h;
            hn[quad * HPAD + j] = h16;            // LDS row = sample
            *hp = h16;                            // hist2 per-block region
            hp += (s < Lmax - 1) ? hstep : 0;

            lds_barrier();   // new h visible; old buffer free
        }
    }
}

// -------- K45 (fused K4+K5): one block per sample.
// NEW (R5): 8 waves (512 thr). Score phase parallelized along TIME: waves
// split by chunk parity (waves 0-3 even 16-t chunks, 4-7 odd) x tile-pair, so
// each wave runs nch/2 chunks instead of nch — halves the per-block serial
// span (the block count is only 64 = 25% of CUs, so span is what matters).
// Softmax is loop-free (512 threads = 512 t). Pool uses 16 t-strides.
__global__ __launch_bounds__(512) void k45_pool(const bf16_t* __restrict__ hist2,
                                                const bf16_t* __restrict__ wh2o_bf,
                                                const float* __restrict__ bh2o,
                                                const float* __restrict__ uw,
                                                const int* __restrict__ lens,
                                                float* __restrict__ out) {
    int b = blockIdx.x;
    int g16 = b >> 2, bl = b & 3;
    int tid = threadIdx.x;
    int lane = tid & 63, w3 = tid >> 6;       // 8 waves
    int quad = lane >> 4, col = lane & 15;
    int len = lens[b];

    int p = w3 >> 2;         // chunk parity (0: even chunks, 1: odd)
    int q = w3 & 3;          // tile pair (n-channels 32q..32q+31)

    __shared__ float smax[TT][4];       // per-tilepair partial scores, 8 KB
    __shared__ float alpha[TT];         // 2 KB
    __shared__ float red[512];          // 2 KB
    __shared__ float red2[16 * 32 * 8]; // pool partials, 16 KB

    const bf16_t* hf = hist2 + (size_t)g16 * TT * 512 + bl * 128;        // fwd
    const bf16_t* hbk = hist2 + (size_t)(16 + g16) * TT * 512 + bl * 128; // bwd

    // this wave's 2 n-tiles (N=128 over 4 tile-pairs)
    int n0 = (q * 2 + 0) * 16 + col;
    int n1 = (q * 2 + 1) * 16 + col;
    float bias0 = bh2o[n0], u0 = uw[n0];
    float bias1 = bh2o[n1], u1 = uw[n1];

    // resident B-fragments (2 n-tiles x 8 kc x 16B = 64 VGPR)
    bf16x8 bw0[8], bw1[8];
#pragma unroll
    for (int kc = 0; kc < 8; ++kc) {
        bw0[kc] = ldb8(wh2o_bf + (size_t)n0 * 256 + kc * 32 + quad * 8);
        bw1[kc] = ldb8(wh2o_bf + (size_t)n1 * 256 + kc * 32 + quad * 8);
    }

    int nch = (len + 15) >> 4;   // len >= 64 -> nch >= 4, both parities busy
    bf16x8 a[8], an[8];
    {   // prime this wave's first chunk (t <= 31+15 <= 511 always valid)
        int t = p * 16 + col;
#pragma unroll
        for (int kc = 0; kc < 4; ++kc) {
            a[kc]     = ldb8(hf  + (size_t)t * 512 + kc * 32 + quad * 8);
            a[kc + 4] = ldb8(hbk + (size_t)t * 512 + kc * 32 + quad * 8);
        }
    }
    for (int ch = p; ch < nch; ch += 2) {
        int t0 = ch * 16;
        // prefetch this wave's next chunk (clamped; t <= 511 stays valid)
        {
            int tn = (ch + 2 < nch ? t0 + 32 : t0) + col;
#pragma unroll
            for (int kc = 0; kc < 4; ++kc) {
                an[kc]     = ldb8(hf  + (size_t)tn * 512 + kc * 32 + quad * 8);
                an[kc + 4] = ldb8(hbk + (size_t)tn * 512 + kc * 32 + quad * 8);
            }
        }
        float p4[4] = {0.f, 0.f, 0.f, 0.f};
#pragma unroll
        for (int tl = 0; tl < 2; ++tl) {
            float bias = tl ? bias1 : bias0;
            float u = tl ? u1 : u0;
            floatx4 acc = {0.f, 0.f, 0.f, 0.f};
#pragma unroll
            for (int kc = 0; kc < 8; ++kc) {
                bf16x8 bw = tl ? bw1[kc] : bw0[kc];
                acc = __builtin_amdgcn_mfma_f32_16x16x32_bf16(a[kc], bw, acc, 0, 0, 0);
            }
#pragma unroll
            for (int r = 0; r < 4; ++r)
                p4[r] += tanh_f(acc[r] + bias) * u;
        }
        // reduce over the 16 cols of this quad group (D rows = t's)
#pragma unroll
        for (int m = 1; m < 16; m <<= 1)
#pragma unroll
            for (int r = 0; r < 4; ++r)
                p4[r] += __shfl_xor(p4[r], m, 64);
        if (col == 0) {
#pragma unroll
            for (int r = 0; r < 4; ++r)
                smax[t0 + quad * 4 + r][q] = p4[r];
        }
#pragma unroll
        for (int kc = 0; kc < 8; ++kc) a[kc] = an[kc];
    }
    __syncthreads();

    // softmax over valid t (loop-free: thread tid <-> t)
    int t = tid;
    float s = -1e30f;
    if (t < len) s = smax[t][0] + smax[t][1] + smax[t][2] + smax[t][3];
    red[tid] = s;
    __syncthreads();
    for (int st = 256; st > 0; st >>= 1) {
        if (tid < st) red[tid] = fmaxf(red[tid], red[tid + st]);
        __syncthreads();
    }
    float mx = red[0];
    __syncthreads();
    float e = (t < len) ? __expf(s - mx) : 0.f;
    alpha[t] = e;
    red[tid] = e;
    __syncthreads();
    for (int st = 256; st > 0; st >>= 1) {
        if (tid < st) red[tid] += red[tid + st];
        __syncthreads();
    }
    float inv = fast_rcp(red[0]);
    __syncthreads();

    // pooled (coalesced): thread = (ts = tid>>5: t stride 16, o = tid&31).
    // dir = o>>4, channels j8..j8+7. Each iter: one 16B bf16x8 load.
    {
        int ts = tid >> 5, o = tid & 31;
        int dirp = o >> 4;
        int j8 = (o & 15) * 8;
        const bf16_t* hbase = (dirp ? hbk : hf) + j8;
        float acc8[8];
#pragma unroll
        for (int ee = 0; ee < 8; ++ee) acc8[ee] = 0.f;
        for (int tt2 = ts; tt2 < len; tt2 += 16) {
            float al = alpha[tt2];
            bf16x8 hv = ldb8(hbase + (size_t)tt2 * 512);
#pragma unroll
            for (int ee = 0; ee < 8; ++ee) acc8[ee] = fmaf(al, (float)hv[ee], acc8[ee]);
        }
#pragma unroll
        for (int ee = 0; ee < 8; ++ee) red2[(ts * 32 + o) * 8 + ee] = acc8[ee];
        __syncthreads();
        if (tid < 256) {
            int c = tid;                       // output channel
            int dir2 = c >> 7, rem = c & 127;
            int oo = dir2 * 16 + (rem >> 3), ee = c & 7;
            float acc = 0.f;
#pragma unroll
            for (int qq = 0; qq < 16; ++qq) acc += red2[(qq * 32 + oo) * 8 + ee];
            out[(size_t)b * 256 + c] = acc * inv;
        }
    }
}

extern "C" void kernel_launch(void* const* d_in, const int* in_sizes, int n_in,
                              void* d_out, int out_size, void* d_ws, size_t ws_size,
                              hipStream_t stream) {
    const int* X       = (const int*)d_in[0];
    const int* lens    = (const int*)d_in[1];
    const float* emb   = (const float*)d_in[3];
    const float* We2i  = (const float*)d_in[4];
    const float* be2i  = (const float*)d_in[5];
    const float* Wihf  = (const float*)d_in[6];
    const float* Whhf  = (const float*)d_in[7];
    const float* bihf  = (const float*)d_in[8];
    const float* bhhf  = (const float*)d_in[9];
    const float* Wihb  = (const float*)d_in[10];
    const float* Whhb  = (const float*)d_in[11];
    const float* bihb  = (const float*)d_in[12];
    const float* bhhb  = (const float*)d_in[13];
    const float* Wh2o  = (const float*)d_in[14];
    const float* bh2o  = (const float*)d_in[15];
    const float* uw    = (const float*)d_in[16];

    char* ws = (char*)d_ws;
    size_t off = 0;
    bf16_t* we_bf = (bf16_t*)(ws + off);   off += (size_t)HH * EE * 2;          // 32 KB
    bf16_t* wih_bf = (bf16_t*)(ws + off);  off += (size_t)2 * 384 * HH * 2;     // 192 KB
    bf16_t* whh_bf = (bf16_t*)(ws + off);  off += (size_t)2 * 384 * HH * 2;     // 192 KB
    bf16_t* wh2o_bf = (bf16_t*)(ws + off); off += (size_t)OO * 256 * 2;         // 64 KB
    float* gxbias = (float*)(ws + off);    off += 768 * 4;                      // 3 KB
    off = (off + 255) & ~(size_t)255;
    bf16_t* gx3 = (bf16_t*)(ws + off);     off += (size_t)32 * TT * 384 * 4 * 2; // 50.3 MB
    bf16_t* hist2 = (bf16_t*)(ws + off);   off += (size_t)32 * TT * 4 * 128 * 2; // 16.8 MB

    float* out = (float*)d_out;

    k0_conv<<<dim3(256), dim3(256), 0, stream>>>(We2i, Wihf, Wihb, Whhf, Whhb,
                                                 Wh2o, bihf, bhhf, bihb, bhhb,
                                                 we_bf, wih_bf, whh_bf, wh2o_bf, gxbias);
    k12_gx<<<dim3(TT), dim3(256), 0, stream>>>(X, emb, we_bf, be2i, wih_bf, gxbias, lens, gx3);
    k3_gru<<<dim3(16, 2), dim3(512), 0, stream>>>(gx3, whh_bf, bhhf, bhhb, lens, hist2);
    k45_pool<<<dim3(BB), dim3(512), 0, stream>>>(hist2, wh2o_bf, bh2o, uw, lens, out);
}